// Round 1
// baseline (2137.203 us; speedup 1.0000x reference)
//
#include <hip/hip_runtime.h>
#include <math.h>

#define B 4
#define S 4096
#define D 1024
#define H 16
#define HD 64
#define WIN 512
#define NW 8
#define G 64
#define G2 128
#define SCALE 0.125f

// ---------------------------------------------------------------- kernel 1: x + pos_emb
__global__ void k_posadd(const float* __restrict__ x, const float* __restrict__ pos,
                         float* __restrict__ xe) {
    int i = blockIdx.x * blockDim.x + threadIdx.x;        // float4 index
    float4 xv = ((const float4*)x)[i];
    int e = i & (S * D / 4 - 1);                          // i % (S*D/4), power of 2
    float4 pv = ((const float4*)pos)[e];
    xv.x += pv.x; xv.y += pv.y; xv.z += pv.z; xv.w += pv.w;
    ((float4*)xe)[i] = xv;
}

// ---------------------------------------------------------------- kernel 2: window attention
// one block per (b, window, head); 512 threads, one query row each.
// whole head-window (512x64 f32) staged in LDS (139 KB); deferred-max online softmax.
__launch_bounds__(512)
__global__ void k_winattn(const float* __restrict__ xe, float* __restrict__ local) {
    int blk = blockIdx.x;
    int h  = blk & 15;
    int wi = (blk >> 4) & 7;
    int b  = blk >> 7;
    __shared__ float kv[WIN][68];                         // stride 68 floats = 272B, 16B aligned
    const float* base = xe + ((size_t)b * S + (size_t)wi * WIN) * D + h * HD;
    int t = threadIdx.x;
    for (int i = t; i < WIN * 16; i += 512) {
        int r = i >> 4, c4 = i & 15;
        *(float4*)(&kv[r][c4 * 4]) = *(const float4*)(base + (size_t)r * D + c4 * 4);
    }
    __syncthreads();

    float q[64];
#pragma unroll
    for (int j4 = 0; j4 < 16; ++j4) {
        float4 v = *(const float4*)(&kv[t][j4 * 4]);
        q[4*j4+0] = v.x * SCALE; q[4*j4+1] = v.y * SCALE;
        q[4*j4+2] = v.z * SCALE; q[4*j4+3] = v.w * SCALE;
    }
    float m = -1e30f, l = 0.f;
    float acc[64] = {};
    for (int k = 0; k < WIN; ++k) {
        float4 row[16];
        float s0 = 0.f, s1 = 0.f, s2 = 0.f, s3 = 0.f;
#pragma unroll
        for (int j4 = 0; j4 < 16; ++j4) {
            float4 v = *(const float4*)(&kv[k][j4 * 4]);
            row[j4] = v;
            s0 = fmaf(q[4*j4+0], v.x, s0);
            s1 = fmaf(q[4*j4+1], v.y, s1);
            s2 = fmaf(q[4*j4+2], v.z, s2);
            s3 = fmaf(q[4*j4+3], v.w, s3);
        }
        float s = (s0 + s1) + (s2 + s3);
        if (s > m + 8.f) {                                 // deferred-max rescale (T13)
            float corr = __expf(m - s);
            m = s;
            l *= corr;
#pragma unroll
            for (int j = 0; j < 64; ++j) acc[j] *= corr;
        }
        float p = __expf(s - m);
        l += p;
#pragma unroll
        for (int j4 = 0; j4 < 16; ++j4) {
            acc[4*j4+0] = fmaf(p, row[j4].x, acc[4*j4+0]);
            acc[4*j4+1] = fmaf(p, row[j4].y, acc[4*j4+1]);
            acc[4*j4+2] = fmaf(p, row[j4].z, acc[4*j4+2]);
            acc[4*j4+3] = fmaf(p, row[j4].w, acc[4*j4+3]);
        }
    }
    float inv = 1.f / l;
    float* outp = local + ((size_t)b * S + (size_t)wi * WIN + t) * D + h * HD;
#pragma unroll
    for (int j4 = 0; j4 < 16; ++j4) {
        *(float4*)(outp + j4 * 4) =
            make_float4(acc[4*j4+0]*inv, acc[4*j4+1]*inv, acc[4*j4+2]*inv, acc[4*j4+3]*inv);
    }
}

// ---------------------------------------------------------------- kernel 3a: conv as split-K GEMM
// partial[kc][bg][n] = sum_din xe[b, 4g+kc, din] * conv_w[n, din, kc]
// grid: 256 blocks = kc(4) x mtile(4 of 64 bg) x ntile(16 of 64 n); 64x64 tile, BK=32.
__launch_bounds__(256)
__global__ void k_conv_part(const float* __restrict__ xe, const float* __restrict__ convw,
                            float* __restrict__ part) {
    int bid = blockIdx.x;
    int nt = bid & 15, mt = (bid >> 4) & 3, kc = bid >> 6;
    __shared__ float As[32][68];
    __shared__ float Bs[32][68];
    int t = threadIdx.x, tx = t & 15, ty = t >> 4;
    float acc[4][4] = {};
    for (int k0 = 0; k0 < 1024; k0 += 32) {
#pragma unroll
        for (int p = 0; p < 2; ++p) {
            int fidx = t + 256 * p;
            int am = fidx >> 3, ak4 = fidx & 7;
            int bg = mt * 64 + am, b = bg >> 6, g = bg & 63;
            float4 v = *(const float4*)(xe + ((size_t)b * S + 4 * g + kc) * D + k0 + ak4 * 4);
            As[ak4*4+0][am] = v.x; As[ak4*4+1][am] = v.y;
            As[ak4*4+2][am] = v.z; As[ak4*4+3][am] = v.w;
        }
#pragma unroll
        for (int p = 0; p < 8; ++p) {
            int bk = t & 31, bn = (t >> 5) + 8 * p;
            Bs[bk][bn] = convw[(size_t)(nt * 64 + bn) * 4096 + (size_t)(k0 + bk) * 4 + kc];
        }
        __syncthreads();
#pragma unroll
        for (int kk = 0; kk < 32; ++kk) {
            float a[4], bb[4];
            *(float4*)a  = *(const float4*)(&As[kk][ty * 4]);
            *(float4*)bb = *(const float4*)(&Bs[kk][tx * 4]);
#pragma unroll
            for (int i = 0; i < 4; ++i)
#pragma unroll
                for (int j = 0; j < 4; ++j)
                    acc[i][j] = fmaf(a[i], bb[j], acc[i][j]);
        }
        __syncthreads();
    }
#pragma unroll
    for (int i = 0; i < 4; ++i) {
        size_t off = ((size_t)kc * 256 + mt * 64 + ty * 4 + i) * 1024 + nt * 64 + tx * 4;
        *(float4*)(part + off) = make_float4(acc[i][0], acc[i][1], acc[i][2], acc[i][3]);
    }
}

// ---------------------------------------------------------------- kernel 3b: assemble gt
__global__ void k_gt(const float* __restrict__ part, const float* __restrict__ convb,
                     const float* __restrict__ gmem, float* __restrict__ gt) {
    int f = blockIdx.x * blockDim.x + threadIdx.x;        // float4 idx, total 131072
    int n4  = f & 255;
    int tok = (f >> 8) & 127;
    int b   = f >> 15;
    float4 v;
    if (tok < 64) {
        v = ((const float4*)convb)[n4];
#pragma unroll
        for (int kc = 0; kc < 4; ++kc) {
            float4 p = ((const float4*)part)[((size_t)kc * 256 + b * 64 + tok) * 256 + n4];
            v.x += p.x; v.y += p.y; v.z += p.z; v.w += p.w;
        }
    } else {
        v = ((const float4*)gmem)[(size_t)(tok - 64) * 256 + n4];
    }
    ((float4*)gt)[f] = v;
}

// ---------------------------------------------------------------- kernel 4: global attention
// one block per (b, head, 256-row s-tile); gt head-slice (128x64) in LDS.
__launch_bounds__(256)
__global__ void k_globattn(const float* __restrict__ xe, const float* __restrict__ gt,
                           float* __restrict__ glob) {
    int bid = blockIdx.x;
    int st = bid & 15, h = (bid >> 4) & 15, b = bid >> 8;
    __shared__ float gts[G2][68];
    int t = threadIdx.x;
#pragma unroll
    for (int p = 0; p < 8; ++p) {
        int fidx = t + 256 * p;
        int r = fidx >> 4, c4 = fidx & 15;
        *(float4*)(&gts[r][c4 * 4]) =
            *(const float4*)(gt + ((size_t)b * G2 + r) * D + h * HD + c4 * 4);
    }
    __syncthreads();
    int s = st * 256 + t;
    const float* qp = xe + ((size_t)b * S + s) * D + h * HD;
    float q[64];
#pragma unroll
    for (int j4 = 0; j4 < 16; ++j4) {
        float4 v = *(const float4*)(qp + j4 * 4);
        q[4*j4+0] = v.x * SCALE; q[4*j4+1] = v.y * SCALE;
        q[4*j4+2] = v.z * SCALE; q[4*j4+3] = v.w * SCALE;
    }
    float m = -1e30f, l = 0.f;
    float acc[64] = {};
    for (int g = 0; g < G2; ++g) {
        float4 row[16];
        float s0 = 0.f, s1 = 0.f, s2 = 0.f, s3 = 0.f;
#pragma unroll
        for (int j4 = 0; j4 < 16; ++j4) {
            float4 v = *(const float4*)(&gts[g][j4 * 4]);
            row[j4] = v;
            s0 = fmaf(q[4*j4+0], v.x, s0);
            s1 = fmaf(q[4*j4+1], v.y, s1);
            s2 = fmaf(q[4*j4+2], v.z, s2);
            s3 = fmaf(q[4*j4+3], v.w, s3);
        }
        float sc = (s0 + s1) + (s2 + s3);
        if (sc > m + 8.f) {
            float corr = __expf(m - sc);
            m = sc;
            l *= corr;
#pragma unroll
            for (int j = 0; j < 64; ++j) acc[j] *= corr;
        }
        float p = __expf(sc - m);
        l += p;
#pragma unroll
        for (int j4 = 0; j4 < 16; ++j4) {
            acc[4*j4+0] = fmaf(p, row[j4].x, acc[4*j4+0]);
            acc[4*j4+1] = fmaf(p, row[j4].y, acc[4*j4+1]);
            acc[4*j4+2] = fmaf(p, row[j4].z, acc[4*j4+2]);
            acc[4*j4+3] = fmaf(p, row[j4].w, acc[4*j4+3]);
        }
    }
    float inv = 1.f / l;
    float* outp = glob + ((size_t)b * S + s) * D + h * HD;
#pragma unroll
    for (int j4 = 0; j4 < 16; ++j4) {
        *(float4*)(outp + j4 * 4) =
            make_float4(acc[4*j4+0]*inv, acc[4*j4+1]*inv, acc[4*j4+2]*inv, acc[4*j4+3]*inv);
    }
}

// ---------------------------------------------------------------- kernels 5/6: big GEMMs
// MODE 0: C = mixed = sig(cat(local,glob)@gate_w + gate_b) blended with local/glob.  K=2048.
// MODE 1: C = A0 @ out_w + out_b.                                                    K=1024.
// 128x128 block tile, BK=32, 256 threads, 8x8 micro-tile.
#define BM 128
#define BN 128
#define BKK 32
#define LDSD 132

template <int MODE>
__launch_bounds__(256)
__global__ void k_gemm(const float* __restrict__ A0, const float* __restrict__ A1,
                       const float* __restrict__ Bw, const float* __restrict__ bias,
                       float* __restrict__ Cout) {
    constexpr int K = (MODE == 0) ? 2048 : 1024;
    __shared__ float As[BKK][LDSD];
    __shared__ float Bs[BKK][LDSD];
    const int t = threadIdx.x;
    const int tx = t & 15, ty = t >> 4;
    const int bn = blockIdx.x * BN, bm = blockIdx.y * BM;
    float acc[8][8] = {};
    for (int k0 = 0; k0 < K; k0 += BKK) {
        const float* Abase;
        int kloc;
        if (MODE == 0) { Abase = (k0 < 1024) ? A0 : A1; kloc = k0 & 1023; }
        else           { Abase = A0;                    kloc = k0; }
#pragma unroll
        for (int p = 0; p < 4; ++p) {
            int fidx = t + 256 * p;
            int am = fidx >> 3, ak4 = fidx & 7;
            float4 v = *(const float4*)(Abase + (size_t)(bm + am) * 1024 + kloc + ak4 * 4);
            As[ak4*4+0][am] = v.x; As[ak4*4+1][am] = v.y;
            As[ak4*4+2][am] = v.z; As[ak4*4+3][am] = v.w;
        }
#pragma unroll
        for (int p = 0; p < 4; ++p) {
            int fidx = t + 256 * p;
            int bk = fidx >> 5, bn4 = fidx & 31;
            float4 v = *(const float4*)(Bw + (size_t)(k0 + bk) * 1024 + bn + bn4 * 4);
            *(float4*)(&Bs[bk][bn4 * 4]) = v;
        }
        __syncthreads();
#pragma unroll
        for (int kk = 0; kk < BKK; ++kk) {
            float a[8], bb[8];
            *(float4*)(a)      = *(const float4*)(&As[kk][ty * 8]);
            *(float4*)(a + 4)  = *(const float4*)(&As[kk][ty * 8 + 4]);
            *(float4*)(bb)     = *(const float4*)(&Bs[kk][tx * 8]);
            *(float4*)(bb + 4) = *(const float4*)(&Bs[kk][tx * 8 + 4]);
#pragma unroll
            for (int i = 0; i < 8; ++i)
#pragma unroll
                for (int j = 0; j < 8; ++j)
                    acc[i][j] = fmaf(a[i], bb[j], acc[i][j]);
        }
        __syncthreads();
    }
    float bias8[8];
#pragma unroll
    for (int j = 0; j < 8; ++j) bias8[j] = bias[bn + tx * 8 + j];
#pragma unroll
    for (int i = 0; i < 8; ++i) {
        size_t row = (size_t)(bm + ty * 8 + i) * 1024 + bn + tx * 8;
        if (MODE == 0) {
            float4 l0 = *(const float4*)(A0 + row), l1 = *(const float4*)(A0 + row + 4);
            float4 g0 = *(const float4*)(A1 + row), g1 = *(const float4*)(A1 + row + 4);
            float lv[8] = {l0.x, l0.y, l0.z, l0.w, l1.x, l1.y, l1.z, l1.w};
            float gv[8] = {g0.x, g0.y, g0.z, g0.w, g1.x, g1.y, g1.z, g1.w};
            float o[8];
#pragma unroll
            for (int j = 0; j < 8; ++j) {
                float mix = 1.f / (1.f + __expf(-(acc[i][j] + bias8[j])));
                o[j] = mix * lv[j] + (1.f - mix) * gv[j];
            }
            *(float4*)(Cout + row)     = make_float4(o[0], o[1], o[2], o[3]);
            *(float4*)(Cout + row + 4) = make_float4(o[4], o[5], o[6], o[7]);
        } else {
            float o[8];
#pragma unroll
            for (int j = 0; j < 8; ++j) o[j] = acc[i][j] + bias8[j];
            *(float4*)(Cout + row)     = make_float4(o[0], o[1], o[2], o[3]);
            *(float4*)(Cout + row + 4) = make_float4(o[4], o[5], o[6], o[7]);
        }
    }
}

// ---------------------------------------------------------------- launch
extern "C" void kernel_launch(void* const* d_in, const int* in_sizes, int n_in,
                              void* d_out, int out_size, void* d_ws, size_t ws_size,
                              hipStream_t stream) {
    (void)in_sizes; (void)n_in; (void)out_size; (void)ws_size;
    const float* x     = (const float*)d_in[0];
    const float* pos   = (const float*)d_in[1];
    const float* gmem  = (const float*)d_in[2];
    const float* convw = (const float*)d_in[3];
    const float* convb = (const float*)d_in[4];
    const float* gatew = (const float*)d_in[5];
    const float* gateb = (const float*)d_in[6];
    const float* outw  = (const float*)d_in[7];
    const float* outb  = (const float*)d_in[8];

    float* ws    = (float*)d_ws;
    float* xe    = ws;                                   // B*S*D          = 16,777,216 f
    float* glob  = ws + (size_t)B * S * D;               // B*S*D
    float* gt    = glob + (size_t)B * S * D;             // B*G2*D         = 524,288 f
    float* part  = gt + (size_t)B * G2 * D;              // 4*256*1024     = 1,048,576 f
    float* local = (float*)d_out;                        // overwritten by final GEMM
    float* mixed = xe;                                   // xe dead after k_globattn

    k_posadd  <<<B * S * D / 4 / 256, 256, 0, stream>>>(x, pos, xe);
    k_winattn <<<B * NW * H, 512, 0, stream>>>(xe, local);
    k_conv_part<<<256, 256, 0, stream>>>(xe, convw, part);
    k_gt      <<<B * G2 * D / 4 / 256, 256, 0, stream>>>(part, convb, gmem, gt);
    k_globattn<<<B * H * (S / 256), 256, 0, stream>>>(xe, gt, glob);
    k_gemm<0> <<<dim3(BN == 128 ? 8 : 8, 128), 256, 0, stream>>>(local, glob, gatew, gateb, mixed);
    k_gemm<1> <<<dim3(8, 128), 256, 0, stream>>>(mixed, nullptr, outw, outb, (float*)d_out);
}

// Round 2
// 1197.718 us; speedup vs baseline: 1.7844x; 1.7844x over previous
//
#include <hip/hip_runtime.h>
#include <math.h>

#define B 4
#define S 4096
#define D 1024
#define H 16
#define HD 64
#define WIN 512
#define NW 8
#define G 64
#define G2 128
#define SCALE 0.125f

typedef __attribute__((ext_vector_type(8))) short bf16x8;
typedef __attribute__((ext_vector_type(4))) float f32x4;

__device__ inline unsigned short f2bf(float f) {
    unsigned u = __builtin_bit_cast(unsigned, f);
    return (unsigned short)((u + 0x7FFFu + ((u >> 16) & 1u)) >> 16);
}

__device__ inline void gload16(const void* g, void* l) {
    __builtin_amdgcn_global_load_lds(
        (const __attribute__((address_space(1))) unsigned*)g,
        (__attribute__((address_space(3))) unsigned*)l, 16, 0, 0);
}

// ---------------------------------------------------------------- kernel 1: x + pos_emb
__global__ void k_posadd(const float* __restrict__ x, const float* __restrict__ pos,
                         float* __restrict__ xe) {
    int i = blockIdx.x * blockDim.x + threadIdx.x;        // float4 index
    float4 xv = ((const float4*)x)[i];
    int e = i & (S * D / 4 - 1);
    float4 pv = ((const float4*)pos)[e];
    xv.x += pv.x; xv.y += pv.y; xv.z += pv.z; xv.w += pv.w;
    ((float4*)xe)[i] = xv;
}

// ---------------------------------------------------------------- weight transpose + bf16
// w: [KD][1024] f32 (in,out)  ->  wT: [1024][KD] bf16  (B^T layout for MFMA GEMM)
template <int KD>
__global__ void k_wtrans(const float* __restrict__ w, unsigned short* __restrict__ wT) {
    __shared__ float tile[32][33];
    int k0 = blockIdx.x * 32, n0 = blockIdx.y * 32;
    int tx = threadIdx.x & 31, ty = threadIdx.x >> 5;     // 32 x 8
#pragma unroll
    for (int i = 0; i < 4; ++i)
        tile[ty + 8 * i][tx] = w[(size_t)(k0 + ty + 8 * i) * 1024 + n0 + tx];
    __syncthreads();
#pragma unroll
    for (int i = 0; i < 4; ++i)
        wT[(size_t)(n0 + ty + 8 * i) * KD + k0 + tx] = f2bf(tile[tx][ty + 8 * i]);
}

// ---------------------------------------------------------------- kernel 2: window attention
__launch_bounds__(512)
__global__ void k_winattn(const float* __restrict__ xe, float* __restrict__ local,
                          unsigned short* __restrict__ local_bf) {
    int blk = blockIdx.x;
    int h  = blk & 15;
    int wi = (blk >> 4) & 7;
    int b  = blk >> 7;
    __shared__ float kv[WIN][68];
    const float* base = xe + ((size_t)b * S + (size_t)wi * WIN) * D + h * HD;
    int t = threadIdx.x;
    for (int i = t; i < WIN * 16; i += 512) {
        int r = i >> 4, c4 = i & 15;
        *(float4*)(&kv[r][c4 * 4]) = *(const float4*)(base + (size_t)r * D + c4 * 4);
    }
    __syncthreads();

    float q[64];
#pragma unroll
    for (int j4 = 0; j4 < 16; ++j4) {
        float4 v = *(const float4*)(&kv[t][j4 * 4]);
        q[4*j4+0] = v.x * SCALE; q[4*j4+1] = v.y * SCALE;
        q[4*j4+2] = v.z * SCALE; q[4*j4+3] = v.w * SCALE;
    }
    float m = -1e30f, l = 0.f;
    float acc[64] = {};
    for (int k = 0; k < WIN; ++k) {
        float4 row[16];
        float s0 = 0.f, s1 = 0.f, s2 = 0.f, s3 = 0.f;
#pragma unroll
        for (int j4 = 0; j4 < 16; ++j4) {
            float4 v = *(const float4*)(&kv[k][j4 * 4]);
            row[j4] = v;
            s0 = fmaf(q[4*j4+0], v.x, s0);
            s1 = fmaf(q[4*j4+1], v.y, s1);
            s2 = fmaf(q[4*j4+2], v.z, s2);
            s3 = fmaf(q[4*j4+3], v.w, s3);
        }
        float s = (s0 + s1) + (s2 + s3);
        if (s > m + 8.f) {                                 // deferred-max rescale (T13)
            float corr = __expf(m - s);
            m = s;
            l *= corr;
#pragma unroll
            for (int j = 0; j < 64; ++j) acc[j] *= corr;
        }
        float p = __expf(s - m);
        l += p;
#pragma unroll
        for (int j4 = 0; j4 < 16; ++j4) {
            acc[4*j4+0] = fmaf(p, row[j4].x, acc[4*j4+0]);
            acc[4*j4+1] = fmaf(p, row[j4].y, acc[4*j4+1]);
            acc[4*j4+2] = fmaf(p, row[j4].z, acc[4*j4+2]);
            acc[4*j4+3] = fmaf(p, row[j4].w, acc[4*j4+3]);
        }
    }
    float inv = 1.f / l;
    size_t rowoff = ((size_t)b * S + (size_t)wi * WIN + t) * D + h * HD;
    float* outp = local + rowoff;
    unsigned short* obf = local_bf + rowoff;
#pragma unroll
    for (int j4 = 0; j4 < 16; ++j4) {
        *(float4*)(outp + j4 * 4) =
            make_float4(acc[4*j4+0]*inv, acc[4*j4+1]*inv, acc[4*j4+2]*inv, acc[4*j4+3]*inv);
    }
#pragma unroll
    for (int j8 = 0; j8 < 8; ++j8) {
        bf16x8 v;
#pragma unroll
        for (int e = 0; e < 8; ++e) v[e] = (short)f2bf(acc[8*j8+e] * inv);
        *(bf16x8*)(obf + 8 * j8) = v;
    }
}

// ---------------------------------------------------------------- kernel 3a: conv as split-K GEMM
__launch_bounds__(256)
__global__ void k_conv_part(const float* __restrict__ xe, const float* __restrict__ convw,
                            float* __restrict__ part) {
    int bid = blockIdx.x;
    int nt = bid & 15, mt = (bid >> 4) & 3, kc = bid >> 6;
    __shared__ float As[32][68];
    __shared__ float Bs[32][68];
    int t = threadIdx.x, tx = t & 15, ty = t >> 4;
    float acc[4][4] = {};
    for (int k0 = 0; k0 < 1024; k0 += 32) {
#pragma unroll
        for (int p = 0; p < 2; ++p) {
            int fidx = t + 256 * p;
            int am = fidx >> 3, ak4 = fidx & 7;
            int bg = mt * 64 + am, b = bg >> 6, g = bg & 63;
            float4 v = *(const float4*)(xe + ((size_t)b * S + 4 * g + kc) * D + k0 + ak4 * 4);
            As[ak4*4+0][am] = v.x; As[ak4*4+1][am] = v.y;
            As[ak4*4+2][am] = v.z; As[ak4*4+3][am] = v.w;
        }
#pragma unroll
        for (int p = 0; p < 8; ++p) {
            int bk = t & 31, bn = (t >> 5) + 8 * p;
            Bs[bk][bn] = convw[(size_t)(nt * 64 + bn) * 4096 + (size_t)(k0 + bk) * 4 + kc];
        }
        __syncthreads();
#pragma unroll
        for (int kk = 0; kk < 32; ++kk) {
            float a[4], bb[4];
            *(float4*)a  = *(const float4*)(&As[kk][ty * 4]);
            *(float4*)bb = *(const float4*)(&Bs[kk][tx * 4]);
#pragma unroll
            for (int i = 0; i < 4; ++i)
#pragma unroll
                for (int j = 0; j < 4; ++j)
                    acc[i][j] = fmaf(a[i], bb[j], acc[i][j]);
        }
        __syncthreads();
    }
#pragma unroll
    for (int i = 0; i < 4; ++i) {
        size_t off = ((size_t)kc * 256 + mt * 64 + ty * 4 + i) * 1024 + nt * 64 + tx * 4;
        *(float4*)(part + off) = make_float4(acc[i][0], acc[i][1], acc[i][2], acc[i][3]);
    }
}

// ---------------------------------------------------------------- kernel 3b: assemble gt
__global__ void k_gt(const float* __restrict__ part, const float* __restrict__ convb,
                     const float* __restrict__ gmem, float* __restrict__ gt) {
    int f = blockIdx.x * blockDim.x + threadIdx.x;
    int n4  = f & 255;
    int tok = (f >> 8) & 127;
    int b   = f >> 15;
    float4 v;
    if (tok < 64) {
        v = ((const float4*)convb)[n4];
#pragma unroll
        for (int kc = 0; kc < 4; ++kc) {
            float4 p = ((const float4*)part)[((size_t)kc * 256 + b * 64 + tok) * 256 + n4];
            v.x += p.x; v.y += p.y; v.z += p.z; v.w += p.w;
        }
    } else {
        v = ((const float4*)gmem)[(size_t)(tok - 64) * 256 + n4];
    }
    ((float4*)gt)[f] = v;
}

// ---------------------------------------------------------------- kernel 4: global attention
__launch_bounds__(256)
__global__ void k_globattn(const float* __restrict__ xe, const float* __restrict__ gt,
                           float* __restrict__ glob, unsigned short* __restrict__ glob_bf) {
    int bid = blockIdx.x;
    int st = bid & 15, h = (bid >> 4) & 15, b = bid >> 8;
    __shared__ float gts[G2][68];
    int t = threadIdx.x;
#pragma unroll
    for (int p = 0; p < 8; ++p) {
        int fidx = t + 256 * p;
        int r = fidx >> 4, c4 = fidx & 15;
        *(float4*)(&gts[r][c4 * 4]) =
            *(const float4*)(gt + ((size_t)b * G2 + r) * D + h * HD + c4 * 4);
    }
    __syncthreads();
    int s = st * 256 + t;
    const float* qp = xe + ((size_t)b * S + s) * D + h * HD;
    float q[64];
#pragma unroll
    for (int j4 = 0; j4 < 16; ++j4) {
        float4 v = *(const float4*)(qp + j4 * 4);
        q[4*j4+0] = v.x * SCALE; q[4*j4+1] = v.y * SCALE;
        q[4*j4+2] = v.z * SCALE; q[4*j4+3] = v.w * SCALE;
    }
    float m = -1e30f, l = 0.f;
    float acc[64] = {};
    for (int g = 0; g < G2; ++g) {
        float4 row[16];
        float s0 = 0.f, s1 = 0.f, s2 = 0.f, s3 = 0.f;
#pragma unroll
        for (int j4 = 0; j4 < 16; ++j4) {
            float4 v = *(const float4*)(&gts[g][j4 * 4]);
            row[j4] = v;
            s0 = fmaf(q[4*j4+0], v.x, s0);
            s1 = fmaf(q[4*j4+1], v.y, s1);
            s2 = fmaf(q[4*j4+2], v.z, s2);
            s3 = fmaf(q[4*j4+3], v.w, s3);
        }
        float sc = (s0 + s1) + (s2 + s3);
        if (sc > m + 8.f) {
            float corr = __expf(m - sc);
            m = sc;
            l *= corr;
#pragma unroll
            for (int j = 0; j < 64; ++j) acc[j] *= corr;
        }
        float p = __expf(sc - m);
        l += p;
#pragma unroll
        for (int j4 = 0; j4 < 16; ++j4) {
            acc[4*j4+0] = fmaf(p, row[j4].x, acc[4*j4+0]);
            acc[4*j4+1] = fmaf(p, row[j4].y, acc[4*j4+1]);
            acc[4*j4+2] = fmaf(p, row[j4].z, acc[4*j4+2]);
            acc[4*j4+3] = fmaf(p, row[j4].w, acc[4*j4+3]);
        }
    }
    float inv = 1.f / l;
    size_t rowoff = ((size_t)b * S + s) * D + h * HD;
    float* outp = glob + rowoff;
    unsigned short* obf = glob_bf + rowoff;
#pragma unroll
    for (int j4 = 0; j4 < 16; ++j4) {
        *(float4*)(outp + j4 * 4) =
            make_float4(acc[4*j4+0]*inv, acc[4*j4+1]*inv, acc[4*j4+2]*inv, acc[4*j4+3]*inv);
    }
#pragma unroll
    for (int j8 = 0; j8 < 8; ++j8) {
        bf16x8 v;
#pragma unroll
        for (int e = 0; e < 8; ++e) v[e] = (short)f2bf(acc[8*j8+e] * inv);
        *(bf16x8*)(obf + 8 * j8) = v;
    }
}

// ---------------------------------------------------------------- kernels 5/6: bf16 MFMA GEMMs
// m97 structure: 128x128 tile, BK=32, 4 waves (each 64x64 via 4x4 16x16x32 frags),
// global_load_lds width-16 staging, linear LDS.
// MODE 0: A = [local_bf | glob_bf] (K=2048) x wTg -> sigmoid blend -> mixed_bf (bf16)
// MODE 1: A = mixed_bf (K=1024) x wTo + out_b    -> d_out (f32)
template <int MODE>
__launch_bounds__(256)
__global__ void k_mgemm(const unsigned short* __restrict__ A0,
                        const unsigned short* __restrict__ A1,
                        const unsigned short* __restrict__ BT,
                        const float* __restrict__ bias,
                        const float* __restrict__ localf,
                        const float* __restrict__ globf,
                        void* __restrict__ Cout) {
    constexpr int K = (MODE == 0) ? 2048 : 1024;
    __shared__ __align__(16) unsigned short As[128 * 32];
    __shared__ __align__(16) unsigned short Bs[128 * 32];
    const int t = threadIdx.x;
    const int wv = t >> 6, ln = t & 63;
    const int lrow = ln & 15, lk = ln >> 4;
    const int wr = wv >> 1, wc = wv & 1;
    const int bn = blockIdx.x * 128, bm = blockIdx.y * 128;
    const int arow = ln >> 2;                 // 0..15 (4 lanes per 32-col row)
    const int acol8 = (ln & 3) * 8;           // bf16 col offset within BK

    f32x4 acc[4][4] = {};

    for (int k0 = 0; k0 < K; k0 += 32) {
        const unsigned short* Ab;
        int kloc;
        if constexpr (MODE == 0) { Ab = (k0 < 1024) ? A0 : A1; kloc = k0 & 1023; }
        else                     { Ab = A0; kloc = k0; }
        // each wave stages 32 rows of A-tile and 32 rows (=cols) of B^T-tile
        gload16(Ab + (size_t)(bm + wv * 32 + arow) * 1024 + kloc + acol8,
                As + wv * 32 * 32);
        gload16(Ab + (size_t)(bm + wv * 32 + 16 + arow) * 1024 + kloc + acol8,
                As + wv * 32 * 32 + 16 * 32);
        gload16(BT + (size_t)(bn + wv * 32 + arow) * K + k0 + acol8,
                Bs + wv * 32 * 32);
        gload16(BT + (size_t)(bn + wv * 32 + 16 + arow) * K + k0 + acol8,
                Bs + wv * 32 * 32 + 16 * 32);
        __syncthreads();
        bf16x8 af[4], bfr[4];
#pragma unroll
        for (int m = 0; m < 4; ++m)
            af[m] = *(const bf16x8*)(As + (wr * 64 + m * 16 + lrow) * 32 + lk * 8);
#pragma unroll
        for (int n = 0; n < 4; ++n)
            bfr[n] = *(const bf16x8*)(Bs + (wc * 64 + n * 16 + lrow) * 32 + lk * 8);
#pragma unroll
        for (int m = 0; m < 4; ++m)
#pragma unroll
            for (int n = 0; n < 4; ++n)
                acc[m][n] = __builtin_amdgcn_mfma_f32_16x16x32_bf16(af[m], bfr[n], acc[m][n], 0, 0, 0);
        __syncthreads();
    }

#pragma unroll
    for (int m = 0; m < 4; ++m) {
#pragma unroll
        for (int n = 0; n < 4; ++n) {
            int col = bn + wc * 64 + n * 16 + lrow;
            float bv = bias[col];
#pragma unroll
            for (int r = 0; r < 4; ++r) {
                int row = bm + wr * 64 + m * 16 + lk * 4 + r;
                size_t off = (size_t)row * 1024 + col;
                float v = acc[m][n][r] + bv;
                if constexpr (MODE == 0) {
                    float mixv = 1.f / (1.f + __expf(-v));
                    float o = mixv * localf[off] + (1.f - mixv) * globf[off];
                    ((unsigned short*)Cout)[off] = f2bf(o);
                } else {
                    ((float*)Cout)[off] = v;
                }
            }
        }
    }
}

// ---------------------------------------------------------------- launch
extern "C" void kernel_launch(void* const* d_in, const int* in_sizes, int n_in,
                              void* d_out, int out_size, void* d_ws, size_t ws_size,
                              hipStream_t stream) {
    (void)in_sizes; (void)n_in; (void)out_size; (void)ws_size;
    const float* x     = (const float*)d_in[0];
    const float* pos   = (const float*)d_in[1];
    const float* gmem  = (const float*)d_in[2];
    const float* convw = (const float*)d_in[3];
    const float* convb = (const float*)d_in[4];
    const float* gatew = (const float*)d_in[5];
    const float* gateb = (const float*)d_in[6];
    const float* outw  = (const float*)d_in[7];
    const float* outb  = (const float*)d_in[8];

    float* ws = (float*)d_ws;
    float* xe    = ws;                                    // 16,777,216 f
    float* globf = xe + 16777216;                         // 16,777,216 f
    float* gt    = globf + 16777216;                      //    524,288 f
    float* part  = gt + 524288;                           //  1,048,576 f
    unsigned short* local_bf = (unsigned short*)(part + 1048576);  // 16M u16
    unsigned short* glob_bf  = local_bf + 16777216;                // 16M u16
    unsigned short* wTg      = glob_bf + 16777216;                 //  2M u16
    unsigned short* wTo      = wTg + 2097152;                      //  1M u16
    unsigned short* mixed_bf = (unsigned short*)xe;       // alias: xe dead after globattn
    float* localf = (float*)d_out;                        // overwritten by final GEMM

    k_posadd  <<<16384, 256, 0, stream>>>(x, pos, xe);
    k_wtrans<2048><<<dim3(64, 32), 256, 0, stream>>>(gatew, wTg);
    k_wtrans<1024><<<dim3(32, 32), 256, 0, stream>>>(outw, wTo);
    k_winattn <<<B * NW * H, 512, 0, stream>>>(xe, localf, local_bf);
    k_conv_part<<<256, 256, 0, stream>>>(xe, convw, part);
    k_gt      <<<512, 256, 0, stream>>>(part, convb, gmem, gt);
    k_globattn<<<B * H * (S / 256), 256, 0, stream>>>(xe, gt, globf, glob_bf);
    k_mgemm<0><<<dim3(8, 128), 256, 0, stream>>>(local_bf, glob_bf, wTg, gateb,
                                                 localf, globf, mixed_bf);
    k_mgemm<1><<<dim3(8, 128), 256, 0, stream>>>(mixed_bf, nullptr, wTo, outb,
                                                 nullptr, nullptr, d_out);
}

// Round 5
// 688.427 us; speedup vs baseline: 3.1045x; 1.7398x over previous
//
#include <hip/hip_runtime.h>
#include <math.h>

#define B 4
#define S 4096
#define D 1024
#define H 16
#define HD 64
#define WIN 512
#define NW 8
#define G 64
#define G2 128
#define SCALE 0.125f

typedef __attribute__((ext_vector_type(8))) short bf16x8;
typedef __attribute__((ext_vector_type(4))) float f32x4;

__device__ inline unsigned short f2bf(float f) {
    unsigned u = __builtin_bit_cast(unsigned, f);
    return (unsigned short)((u + 0x7FFFu + ((u >> 16) & 1u)) >> 16);
}

__device__ inline unsigned long long pack4bf(float a, float b, float c, float d) {
    return (unsigned long long)f2bf(a) | ((unsigned long long)f2bf(b) << 16) |
           ((unsigned long long)f2bf(c) << 32) | ((unsigned long long)f2bf(d) << 48);
}

__device__ inline void gload16(const void* g, void* l) {
    __builtin_amdgcn_global_load_lds(
        (const __attribute__((address_space(1))) unsigned*)g,
        (__attribute__((address_space(3))) unsigned*)l, 16, 0, 0);
}

// ---------------------------------------------------------------- kernel 1: x + pos_emb
__global__ void k_posadd(const float* __restrict__ x, const float* __restrict__ pos,
                         float* __restrict__ xe) {
    int i = blockIdx.x * blockDim.x + threadIdx.x;
    float4 xv = ((const float4*)x)[i];
    int e = i & (S * D / 4 - 1);
    float4 pv = ((const float4*)pos)[e];
    xv.x += pv.x; xv.y += pv.y; xv.z += pv.z; xv.w += pv.w;
    ((float4*)xe)[i] = xv;
}

// ---------------------------------------------------------------- weight transpose + bf16
template <int KD>
__global__ void k_wtrans(const float* __restrict__ w, unsigned short* __restrict__ wT) {
    __shared__ float tile[32][33];
    int k0 = blockIdx.x * 32, n0 = blockIdx.y * 32;
    int tx = threadIdx.x & 31, ty = threadIdx.x >> 5;
#pragma unroll
    for (int i = 0; i < 4; ++i)
        tile[ty + 8 * i][tx] = w[(size_t)(k0 + ty + 8 * i) * 1024 + n0 + tx];
    __syncthreads();
#pragma unroll
    for (int i = 0; i < 4; ++i)
        wT[(size_t)(n0 + ty + 8 * i) * KD + k0 + tx] = f2bf(tile[tx][ty + 8 * i]);
}

// ---------------------------------------------------------------- kernel 2: MFMA window attention
// grid: (qt, h, wi, b); block 256 = 4 waves, each wave 32 q-rows of a 128-row Q-tile.
// Swapped QK^T (scores col = q-row) -> in-lane softmax; P via wave-private LDS; PV MFMA.
__launch_bounds__(256)
__global__ void k_winattn(const float* __restrict__ xe, float* __restrict__ local,
                          unsigned short* __restrict__ local_bf) {
    int blk = blockIdx.x;
    int qt = blk & 3, h = (blk >> 2) & 15, wi = (blk >> 6) & 7, b = blk >> 9;

    __shared__ __align__(16) unsigned char lds[66048];
    unsigned char* Qs = lds;                 // [128][64] bf16, swz by q       16 KB
    unsigned char* Kb = lds + 16384;         // 2x [64][64] bf16, swz by key   16 KB
    unsigned char* Vb = lds + 32768;         // 2x [64 d][64 key] bf16, swz d>>2 16 KB
    unsigned char* Pb = lds + 49152;         // 4x [32][64] bf16, swz by q     16 KB
    float* corr = (float*)(lds + 65536);     // 4 x 32 floats

    const int t = threadIdx.x;
    const int wv = t >> 6, l = t & 63;
    const int g = l >> 4, c = l & 15;

    const float* wbase = xe + ((size_t)b * S + (size_t)wi * WIN) * D + h * HD;

    // ---- stage Q (pre-scaled)
#pragma unroll
    for (int p = 0; p < 8; ++p) {
        int i = t + 256 * p;
        int q = i >> 4, c4 = i & 15;
        float4 v = *(const float4*)(wbase + (size_t)(qt * 128 + q) * D + c4 * 4);
        *(unsigned long long*)(Qs + q * 128 + ((c4 * 8) ^ ((q & 7) << 4))) =
            pack4bf(v.x * SCALE, v.y * SCALE, v.z * SCALE, v.w * SCALE);
    }

    auto stage_kv = [&](int kt, int bb) {
        unsigned char* kb = Kb + bb * 8192;
        unsigned char* vb = Vb + bb * 8192;
#pragma unroll
        for (int p = 0; p < 4; ++p) {
            int i = t + 256 * p;
            int key = i >> 4, c4 = i & 15;
            float4 v = *(const float4*)(wbase + (size_t)(kt * 64 + key) * D + c4 * 4);
            *(unsigned long long*)(kb + key * 128 + ((c4 * 8) ^ ((key & 7) << 4))) =
                pack4bf(v.x, v.y, v.z, v.w);
            int swz = (c4 & 7) << 4;
            int d0 = c4 * 4;
            *(unsigned short*)(vb + (d0 + 0) * 128 + ((key * 2) ^ swz)) = f2bf(v.x);
            *(unsigned short*)(vb + (d0 + 1) * 128 + ((key * 2) ^ swz)) = f2bf(v.y);
            *(unsigned short*)(vb + (d0 + 2) * 128 + ((key * 2) ^ swz)) = f2bf(v.z);
            *(unsigned short*)(vb + (d0 + 3) * 128 + ((key * 2) ^ swz)) = f2bf(v.w);
        }
    };

    stage_kv(0, 0);
    __syncthreads();

    bf16x8 QB[2][2];                         // [ni][ds]: Q[q = wv*32+ni*16+c][ds*32+g*8 ..]
#pragma unroll
    for (int ni = 0; ni < 2; ++ni)
#pragma unroll
        for (int ds = 0; ds < 2; ++ds) {
            int q = wv * 32 + ni * 16 + c;
            QB[ni][ds] = *(const bf16x8*)(Qs + q * 128 + ((ds * 64 + g * 16) ^ ((q & 7) << 4)));
        }

    float m_run[2] = {-1e30f, -1e30f};
    float l_run[2] = {0.f, 0.f};
    f32x4 acc[2][4] = {};                    // [mf][nf]; rows mf*16+4g+r, cols nf*16+c
    unsigned char* Pw = Pb + wv * 4096;
    float* corw = corr + wv * 32;

    for (int kt = 0; kt < 8; ++kt) {
        int bb = kt & 1;
        if (kt < 7) stage_kv(kt + 1, bb ^ 1);

        unsigned char* kb = Kb + bb * 8192;
        unsigned char* vb = Vb + bb * 8192;
        bf16x8 KA[4][2];                     // [mi][ds]: K[key = mi*16+c][ds*32+g*8 ..]
#pragma unroll
        for (int mi = 0; mi < 4; ++mi)
#pragma unroll
            for (int ds = 0; ds < 2; ++ds) {
                int key = mi * 16 + c;
                KA[mi][ds] = *(const bf16x8*)(kb + key * 128 + ((ds * 64 + g * 16) ^ ((key & 7) << 4)));
            }
        f32x4 sc[4][2] = {};                 // [mi][ni]: score[key=mi*16+4g+r][q=ni*16+c]
#pragma unroll
        for (int mi = 0; mi < 4; ++mi)
#pragma unroll
            for (int ni = 0; ni < 2; ++ni) {
                sc[mi][ni] = __builtin_amdgcn_mfma_f32_16x16x32_bf16(KA[mi][0], QB[ni][0], sc[mi][ni], 0, 0, 0);
                sc[mi][ni] = __builtin_amdgcn_mfma_f32_16x16x32_bf16(KA[mi][1], QB[ni][1], sc[mi][ni], 0, 0, 0);
            }
        // ---- online softmax (per q = ni*16+c, keys spread over g and mi,r)
#pragma unroll
        for (int ni = 0; ni < 2; ++ni) {
            float mt = sc[0][ni][0];
#pragma unroll
            for (int mi = 0; mi < 4; ++mi)
#pragma unroll
                for (int r = 0; r < 4; ++r) mt = fmaxf(mt, sc[mi][ni][r]);
            mt = fmaxf(mt, __shfl_xor(mt, 16));
            mt = fmaxf(mt, __shfl_xor(mt, 32));
            float mnew = fmaxf(m_run[ni], mt);
            float co = __expf(m_run[ni] - mnew);
            m_run[ni] = mnew;
            float ps = 0.f;
            int q = ni * 16 + c;
#pragma unroll
            for (int mi = 0; mi < 4; ++mi) {
                float p0 = __expf(sc[mi][ni][0] - mnew);
                float p1 = __expf(sc[mi][ni][1] - mnew);
                float p2 = __expf(sc[mi][ni][2] - mnew);
                float p3 = __expf(sc[mi][ni][3] - mnew);
                ps += (p0 + p1) + (p2 + p3);
                *(unsigned long long*)(Pw + q * 128 + ((2 * (mi * 16 + g * 4)) ^ ((q & 7) << 4))) =
                    pack4bf(p0, p1, p2, p3);
            }
            ps += __shfl_xor(ps, 16);
            ps += __shfl_xor(ps, 32);
            l_run[ni] = l_run[ni] * co + ps;
            if (g == 0) corw[q] = co;
        }
        // ---- rescale O accumulator (corr broadcast: same addr across 16 lanes = free)
#pragma unroll
        for (int mf = 0; mf < 2; ++mf) {
            float cr0 = corw[mf * 16 + g * 4 + 0];
            float cr1 = corw[mf * 16 + g * 4 + 1];
            float cr2 = corw[mf * 16 + g * 4 + 2];
            float cr3 = corw[mf * 16 + g * 4 + 3];
#pragma unroll
            for (int nf = 0; nf < 4; ++nf) {
                acc[mf][nf][0] *= cr0; acc[mf][nf][1] *= cr1;
                acc[mf][nf][2] *= cr2; acc[mf][nf][3] *= cr3;
            }
        }
        // ---- PV
        bf16x8 PA[2][2], VBf[4][2];
#pragma unroll
        for (int mf = 0; mf < 2; ++mf)
#pragma unroll
            for (int ks = 0; ks < 2; ++ks) {
                int q = mf * 16 + c;
                PA[mf][ks] = *(const bf16x8*)(Pw + q * 128 + ((ks * 64 + g * 16) ^ ((q & 7) << 4)));
            }
#pragma unroll
        for (int nf = 0; nf < 4; ++nf)
#pragma unroll
            for (int ks = 0; ks < 2; ++ks) {
                int d = nf * 16 + c;
                VBf[nf][ks] = *(const bf16x8*)(vb + d * 128 + ((ks * 64 + g * 16) ^ (((d >> 2) & 7) << 4)));
            }
#pragma unroll
        for (int mf = 0; mf < 2; ++mf)
#pragma unroll
            for (int nf = 0; nf < 4; ++nf) {
                acc[mf][nf] = __builtin_amdgcn_mfma_f32_16x16x32_bf16(PA[mf][0], VBf[nf][0], acc[mf][nf], 0, 0, 0);
                acc[mf][nf] = __builtin_amdgcn_mfma_f32_16x16x32_bf16(PA[mf][1], VBf[nf][1], acc[mf][nf], 0, 0, 0);
            }
        __syncthreads();
    }

    if (g == 0) { corw[c] = 1.f / l_run[0]; corw[16 + c] = 1.f / l_run[1]; }
#pragma unroll
    for (int mf = 0; mf < 2; ++mf) {
        float iv[4];
#pragma unroll
        for (int r = 0; r < 4; ++r) iv[r] = corw[mf * 16 + g * 4 + r];
#pragma unroll
        for (int r = 0; r < 4; ++r) {
            size_t row = (size_t)b * S + (size_t)wi * WIN + qt * 128 + wv * 32 + mf * 16 + g * 4 + r;
#pragma unroll
            for (int nf = 0; nf < 4; ++nf) {
                int col = h * HD + nf * 16 + c;
                float o = acc[mf][nf][r] * iv[r];
                local[row * D + col] = o;
                local_bf[row * D + col] = f2bf(o);
            }
        }
    }
}

// ---------------------------------------------------------------- kernel 3a: conv as split-K GEMM
__launch_bounds__(256)
__global__ void k_conv_part(const float* __restrict__ xe, const float* __restrict__ convw,
                            float* __restrict__ part) {
    int bid = blockIdx.x;
    int nt = bid & 15, mt = (bid >> 4) & 3, kc = bid >> 6;
    __shared__ float As[32][68];
    __shared__ float Bs[32][68];
    int t = threadIdx.x, tx = t & 15, ty = t >> 4;
    float acc[4][4] = {};
    for (int k0 = 0; k0 < 1024; k0 += 32) {
#pragma unroll
        for (int p = 0; p < 2; ++p) {
            int fidx = t + 256 * p;
            int am = fidx >> 3, ak4 = fidx & 7;
            int bg = mt * 64 + am, b = bg >> 6, g = bg & 63;
            float4 v = *(const float4*)(xe + ((size_t)b * S + 4 * g + kc) * D + k0 + ak4 * 4);
            As[ak4*4+0][am] = v.x; As[ak4*4+1][am] = v.y;
            As[ak4*4+2][am] = v.z; As[ak4*4+3][am] = v.w;
        }
#pragma unroll
        for (int p = 0; p < 8; ++p) {
            int bk = t & 31, bn = (t >> 5) + 8 * p;
            Bs[bk][bn] = convw[(size_t)(nt * 64 + bn) * 4096 + (size_t)(k0 + bk) * 4 + kc];
        }
        __syncthreads();
#pragma unroll
        for (int kk = 0; kk < 32; ++kk) {
            float a[4], bb[4];
            *(float4*)a  = *(const float4*)(&As[kk][ty * 4]);
            *(float4*)bb = *(const float4*)(&Bs[kk][tx * 4]);
#pragma unroll
            for (int i = 0; i < 4; ++i)
#pragma unroll
                for (int j = 0; j < 4; ++j)
                    acc[i][j] = fmaf(a[i], bb[j], acc[i][j]);
        }
        __syncthreads();
    }
#pragma unroll
    for (int i = 0; i < 4; ++i) {
        size_t off = ((size_t)kc * 256 + mt * 64 + ty * 4 + i) * 1024 + nt * 64 + tx * 4;
        *(float4*)(part + off) = make_float4(acc[i][0], acc[i][1], acc[i][2], acc[i][3]);
    }
}

// ---------------------------------------------------------------- kernel 3b: assemble gt
__global__ void k_gt(const float* __restrict__ part, const float* __restrict__ convb,
                     const float* __restrict__ gmem, float* __restrict__ gt) {
    int f = blockIdx.x * blockDim.x + threadIdx.x;
    int n4  = f & 255;
    int tok = (f >> 8) & 127;
    int b   = f >> 15;
    float4 v;
    if (tok < 64) {
        v = ((const float4*)convb)[n4];
#pragma unroll
        for (int kc = 0; kc < 4; ++kc) {
            float4 p = ((const float4*)part)[((size_t)kc * 256 + b * 64 + tok) * 256 + n4];
            v.x += p.x; v.y += p.y; v.z += p.z; v.w += p.w;
        }
    } else {
        v = ((const float4*)gmem)[(size_t)(tok - 64) * 256 + n4];
    }
    ((float4*)gt)[f] = v;
}

// ---------------------------------------------------------------- kernel 4: global attention
__launch_bounds__(256)
__global__ void k_globattn(const float* __restrict__ xe, const float* __restrict__ gt,
                           float* __restrict__ glob, unsigned short* __restrict__ glob_bf) {
    int bid = blockIdx.x;
    int st = bid & 15, h = (bid >> 4) & 15, b = bid >> 8;
    __shared__ float gts[G2][68];
    int t = threadIdx.x;
#pragma unroll
    for (int p = 0; p < 8; ++p) {
        int fidx = t + 256 * p;
        int r = fidx >> 4, c4 = fidx & 15;
        *(float4*)(&gts[r][c4 * 4]) =
            *(const float4*)(gt + ((size_t)b * G2 + r) * D + h * HD + c4 * 4);
    }
    __syncthreads();
    int s = st * 256 + t;
    const float* qp = xe + ((size_t)b * S + s) * D + h * HD;
    float q[64];
#pragma unroll
    for (int j4 = 0; j4 < 16; ++j4) {
        float4 v = *(const float4*)(qp + j4 * 4);
        q[4*j4+0] = v.x * SCALE; q[4*j4+1] = v.y * SCALE;
        q[4*j4+2] = v.z * SCALE; q[4*j4+3] = v.w * SCALE;
    }
    float m = -1e30f, l = 0.f;
    float acc[64] = {};
    for (int g = 0; g < G2; ++g) {
        float4 row[16];
        float s0 = 0.f, s1 = 0.f, s2 = 0.f, s3 = 0.f;
#pragma unroll
        for (int j4 = 0; j4 < 16; ++j4) {
            float4 v = *(const float4*)(&gts[g][j4 * 4]);
            row[j4] = v;
            s0 = fmaf(q[4*j4+0], v.x, s0);
            s1 = fmaf(q[4*j4+1], v.y, s1);
            s2 = fmaf(q[4*j4+2], v.z, s2);
            s3 = fmaf(q[4*j4+3], v.w, s3);
        }
        float sc = (s0 + s1) + (s2 + s3);
        if (sc > m + 8.f) {
            float corr = __expf(m - sc);
            m = sc;
            l *= corr;
#pragma unroll
            for (int j = 0; j < 64; ++j) acc[j] *= corr;
        }
        float p = __expf(sc - m);
        l += p;
#pragma unroll
        for (int j4 = 0; j4 < 16; ++j4) {
            acc[4*j4+0] = fmaf(p, row[j4].x, acc[4*j4+0]);
            acc[4*j4+1] = fmaf(p, row[j4].y, acc[4*j4+1]);
            acc[4*j4+2] = fmaf(p, row[j4].z, acc[4*j4+2]);
            acc[4*j4+3] = fmaf(p, row[j4].w, acc[4*j4+3]);
        }
    }
    float inv = 1.f / l;
    size_t rowoff = ((size_t)b * S + s) * D + h * HD;
    float* outp = glob + rowoff;
    unsigned short* obf = glob_bf + rowoff;
#pragma unroll
    for (int j4 = 0; j4 < 16; ++j4) {
        *(float4*)(outp + j4 * 4) =
            make_float4(acc[4*j4+0]*inv, acc[4*j4+1]*inv, acc[4*j4+2]*inv, acc[4*j4+3]*inv);
    }
#pragma unroll
    for (int j8 = 0; j8 < 8; ++j8) {
        bf16x8 v;
#pragma unroll
        for (int e = 0; e < 8; ++e) v[e] = (short)f2bf(acc[8*j8+e] * inv);
        *(bf16x8*)(obf + 8 * j8) = v;
    }
}

// ---------------------------------------------------------------- kernels 5/6: bf16 MFMA GEMMs
template <int MODE>
__launch_bounds__(256)
__global__ void k_mgemm(const unsigned short* __restrict__ A0,
                        const unsigned short* __restrict__ A1,
                        const unsigned short* __restrict__ BT,
                        const float* __restrict__ bias,
                        const float* __restrict__ localf,
                        const float* __restrict__ globf,
                        void* __restrict__ Cout) {
    constexpr int K = (MODE == 0) ? 2048 : 1024;
    __shared__ __align__(16) unsigned short As[128 * 32];
    __shared__ __align__(16) unsigned short Bs[128 * 32];
    const int t = threadIdx.x;
    const int wv = t >> 6, ln = t & 63;
    const int lrow = ln & 15, lk = ln >> 4;
    const int wr = wv >> 1, wc = wv & 1;
    const int bn = blockIdx.x * 128, bm = blockIdx.y * 128;
    const int arow = ln >> 2;
    const int acol8 = (ln & 3) * 8;

    f32x4 acc[4][4] = {};

    for (int k0 = 0; k0 < K; k0 += 32) {
        const unsigned short* Ab;
        int kloc;
        if constexpr (MODE == 0) { Ab = (k0 < 1024) ? A0 : A1; kloc = k0 & 1023; }
        else                     { Ab = A0; kloc = k0; }
        gload16(Ab + (size_t)(bm + wv * 32 + arow) * 1024 + kloc + acol8,
                As + wv * 32 * 32);
        gload16(Ab + (size_t)(bm + wv * 32 + 16 + arow) * 1024 + kloc + acol8,
                As + wv * 32 * 32 + 16 * 32);
        gload16(BT + (size_t)(bn + wv * 32 + arow) * K + k0 + acol8,
                Bs + wv * 32 * 32);
        gload16(BT + (size_t)(bn + wv * 32 + 16 + arow) * K + k0 + acol8,
                Bs + wv * 32 * 32 + 16 * 32);
        __syncthreads();
        bf16x8 af[4], bfr[4];
#pragma unroll
        for (int m = 0; m < 4; ++m)
            af[m] = *(const bf16x8*)(As + (wr * 64 + m * 16 + lrow) * 32 + lk * 8);
#pragma unroll
        for (int n = 0; n < 4; ++n)
            bfr[n] = *(const bf16x8*)(Bs + (wc * 64 + n * 16 + lrow) * 32 + lk * 8);
#pragma unroll
        for (int m = 0; m < 4; ++m)
#pragma unroll
            for (int n = 0; n < 4; ++n)
                acc[m][n] = __builtin_amdgcn_mfma_f32_16x16x32_bf16(af[m], bfr[n], acc[m][n], 0, 0, 0);
        __syncthreads();
    }

#pragma unroll
    for (int m = 0; m < 4; ++m) {
#pragma unroll
        for (int n = 0; n < 4; ++n) {
            int col = bn + wc * 64 + n * 16 + lrow;
            float bv = bias[col];
#pragma unroll
            for (int r = 0; r < 4; ++r) {
                int row = bm + wr * 64 + m * 16 + lk * 4 + r;
                size_t off = (size_t)row * 1024 + col;
                float v = acc[m][n][r] + bv;
                if constexpr (MODE == 0) {
                    float mixv = 1.f / (1.f + __expf(-v));
                    float o = mixv * localf[off] + (1.f - mixv) * globf[off];
                    ((unsigned short*)Cout)[off] = f2bf(o);
                } else {
                    ((float*)Cout)[off] = v;
                }
            }
        }
    }
}

// ---------------------------------------------------------------- launch
extern "C" void kernel_launch(void* const* d_in, const int* in_sizes, int n_in,
                              void* d_out, int out_size, void* d_ws, size_t ws_size,
                              hipStream_t stream) {
    (void)in_sizes; (void)n_in; (void)out_size; (void)ws_size;
    const float* x     = (const float*)d_in[0];
    const float* pos   = (const float*)d_in[1];
    const float* gmem  = (const float*)d_in[2];
    const float* convw = (const float*)d_in[3];
    const float* convb = (const float*)d_in[4];
    const float* gatew = (const float*)d_in[5];
    const float* gateb = (const float*)d_in[6];
    const float* outw  = (const float*)d_in[7];
    const float* outb  = (const float*)d_in[8];

    float* ws = (float*)d_ws;
    float* xe    = ws;                                    // 16,777,216 f
    float* globf = xe + 16777216;                         // 16,777,216 f
    float* gt    = globf + 16777216;                      //    524,288 f
    float* part  = gt + 524288;                           //  1,048,576 f
    unsigned short* local_bf = (unsigned short*)(part + 1048576);  // 16M u16
    unsigned short* glob_bf  = local_bf + 16777216;                // 16M u16
    unsigned short* wTg      = glob_bf + 16777216;                 //  2M u16
    unsigned short* wTo      = wTg + 2097152;                      //  1M u16
    unsigned short* mixed_bf = (unsigned short*)xe;       // alias: xe dead after globattn
    float* localf = (float*)d_out;                        // overwritten by final GEMM

    k_posadd  <<<16384, 256, 0, stream>>>(x, pos, xe);
    k_wtrans<2048><<<dim3(64, 32), 256, 0, stream>>>(gatew, wTg);
    k_wtrans<1024><<<dim3(32, 32), 256, 0, stream>>>(outw, wTo);
    k_winattn <<<B * NW * H * 4, 256, 0, stream>>>(xe, localf, local_bf);
    k_conv_part<<<256, 256, 0, stream>>>(xe, convw, part);
    k_gt      <<<512, 256, 0, stream>>>(part, convb, gmem, gt);
    k_globattn<<<B * H * (S / 256), 256, 0, stream>>>(xe, gt, globf, glob_bf);
    k_mgemm<0><<<dim3(8, 128), 256, 0, stream>>>(local_bf, glob_bf, wTg, gateb,
                                                 localf, globf, mixed_bf);
    k_mgemm<1><<<dim3(8, 128), 256, 0, stream>>>(mixed_bf, nullptr, wTo, outb,
                                                 nullptr, nullptr, d_out);
}

// Round 7
// 566.046 us; speedup vs baseline: 3.7757x; 1.2162x over previous
//
#include <hip/hip_runtime.h>
#include <math.h>

#define B 4
#define S 4096
#define D 1024
#define H 16
#define HD 64
#define WIN 512
#define NW 8
#define G 64
#define G2 128
#define SCALE 0.125f

typedef __attribute__((ext_vector_type(8))) short bf16x8;
typedef __attribute__((ext_vector_type(4))) float f32x4;

__device__ inline unsigned short f2bf(float f) {
    unsigned u = __builtin_bit_cast(unsigned, f);
    return (unsigned short)((u + 0x7FFFu + ((u >> 16) & 1u)) >> 16);
}

__device__ inline unsigned long long pack4bf(float a, float b, float c, float d) {
    return (unsigned long long)f2bf(a) | ((unsigned long long)f2bf(b) << 16) |
           ((unsigned long long)f2bf(c) << 32) | ((unsigned long long)f2bf(d) << 48);
}

__device__ inline void gload16(const void* g, void* l) {
    __builtin_amdgcn_global_load_lds(
        (const __attribute__((address_space(1))) unsigned*)g,
        (__attribute__((address_space(3))) unsigned*)l, 16, 0, 0);
}

// compiler-only ordering fence for LDS write->read hand-offs (HW DS is in-order per wave)
#define LDS_FENCE() asm volatile("" ::: "memory")

// ---------------------------------------------------------------- kernel 1: x + pos_emb
__global__ void k_posadd(const float* __restrict__ x, const float* __restrict__ pos,
                         float* __restrict__ xe) {
    int i = blockIdx.x * blockDim.x + threadIdx.x;
    float4 xv = ((const float4*)x)[i];
    int e = i & (S * D / 4 - 1);
    float4 pv = ((const float4*)pos)[e];
    xv.x += pv.x; xv.y += pv.y; xv.z += pv.z; xv.w += pv.w;
    ((float4*)xe)[i] = xv;
}

// ---------------------------------------------------------------- weight transpose + bf16
template <int KD>
__global__ void k_wtrans(const float* __restrict__ w, unsigned short* __restrict__ wT) {
    __shared__ float tile[32][33];
    int k0 = blockIdx.x * 32, n0 = blockIdx.y * 32;
    int tx = threadIdx.x & 31, ty = threadIdx.x >> 5;
#pragma unroll
    for (int i = 0; i < 4; ++i)
        tile[ty + 8 * i][tx] = w[(size_t)(k0 + ty + 8 * i) * 1024 + n0 + tx];
    __syncthreads();
#pragma unroll
    for (int i = 0; i < 4; ++i)
        wT[(size_t)(n0 + ty + 8 * i) * KD + k0 + tx] = f2bf(tile[tx][ty + 8 * i]);
}

// ---------------------------------------------------------------- kernel 2: MFMA window attention
__launch_bounds__(256)
__global__ void k_winattn(const float* __restrict__ xe, float* __restrict__ local,
                          unsigned short* __restrict__ local_bf) {
    int blk = blockIdx.x;
    int qt = blk & 3, h = (blk >> 2) & 15, wi = (blk >> 6) & 7, b = blk >> 9;

    __shared__ __align__(16) unsigned char lds[66048];
    unsigned char* Qs = lds;                 // [128][64] bf16, swz by q       16 KB
    unsigned char* Kb = lds + 16384;         // 2x [64][64] bf16, swz by key   16 KB
    unsigned char* Vb = lds + 32768;         // 2x [64 d][64 key] bf16, swz d>>2 16 KB
    unsigned char* Pb = lds + 49152;         // 4x [32][64] bf16, swz by q     16 KB
    float* corr = (float*)(lds + 65536);     // 4 x 32 floats

    const int t = threadIdx.x;
    const int wv = t >> 6, l = t & 63;
    const int g = l >> 4, c = l & 15;

    const float* wbase = xe + ((size_t)b * S + (size_t)wi * WIN) * D + h * HD;

#pragma unroll
    for (int p = 0; p < 8; ++p) {
        int i = t + 256 * p;
        int q = i >> 4, c4 = i & 15;
        float4 v = *(const float4*)(wbase + (size_t)(qt * 128 + q) * D + c4 * 4);
        *(unsigned long long*)(Qs + q * 128 + ((c4 * 8) ^ ((q & 7) << 4))) =
            pack4bf(v.x * SCALE, v.y * SCALE, v.z * SCALE, v.w * SCALE);
    }

    auto stage_kv = [&](int kt, int bb) {
        unsigned char* kb = Kb + bb * 8192;
        unsigned char* vb = Vb + bb * 8192;
#pragma unroll
        for (int p = 0; p < 4; ++p) {
            int i = t + 256 * p;
            int key = i >> 4, c4 = i & 15;
            float4 v = *(const float4*)(wbase + (size_t)(kt * 64 + key) * D + c4 * 4);
            *(unsigned long long*)(kb + key * 128 + ((c4 * 8) ^ ((key & 7) << 4))) =
                pack4bf(v.x, v.y, v.z, v.w);
            int swz = (c4 & 7) << 4;
            int d0 = c4 * 4;
            *(unsigned short*)(vb + (d0 + 0) * 128 + ((key * 2) ^ swz)) = f2bf(v.x);
            *(unsigned short*)(vb + (d0 + 1) * 128 + ((key * 2) ^ swz)) = f2bf(v.y);
            *(unsigned short*)(vb + (d0 + 2) * 128 + ((key * 2) ^ swz)) = f2bf(v.z);
            *(unsigned short*)(vb + (d0 + 3) * 128 + ((key * 2) ^ swz)) = f2bf(v.w);
        }
    };

    stage_kv(0, 0);
    __syncthreads();

    bf16x8 QB[2][2];
#pragma unroll
    for (int ni = 0; ni < 2; ++ni)
#pragma unroll
        for (int ds = 0; ds < 2; ++ds) {
            int q = wv * 32 + ni * 16 + c;
            QB[ni][ds] = *(const bf16x8*)(Qs + q * 128 + ((ds * 64 + g * 16) ^ ((q & 7) << 4)));
        }

    float m_run[2] = {-1e30f, -1e30f};
    float l_run[2] = {0.f, 0.f};
    f32x4 acc[2][4] = {};
    unsigned char* Pw = Pb + wv * 4096;
    float* corw = corr + wv * 32;

    for (int kt = 0; kt < 8; ++kt) {
        int bb = kt & 1;
        if (kt < 7) stage_kv(kt + 1, bb ^ 1);

        unsigned char* kb = Kb + bb * 8192;
        unsigned char* vb = Vb + bb * 8192;
        bf16x8 KA[4][2];
#pragma unroll
        for (int mi = 0; mi < 4; ++mi)
#pragma unroll
            for (int ds = 0; ds < 2; ++ds) {
                int key = mi * 16 + c;
                KA[mi][ds] = *(const bf16x8*)(kb + key * 128 + ((ds * 64 + g * 16) ^ ((key & 7) << 4)));
            }
        f32x4 sc[4][2] = {};
#pragma unroll
        for (int mi = 0; mi < 4; ++mi)
#pragma unroll
            for (int ni = 0; ni < 2; ++ni) {
                sc[mi][ni] = __builtin_amdgcn_mfma_f32_16x16x32_bf16(KA[mi][0], QB[ni][0], sc[mi][ni], 0, 0, 0);
                sc[mi][ni] = __builtin_amdgcn_mfma_f32_16x16x32_bf16(KA[mi][1], QB[ni][1], sc[mi][ni], 0, 0, 0);
            }
#pragma unroll
        for (int ni = 0; ni < 2; ++ni) {
            float mt = sc[0][ni][0];
#pragma unroll
            for (int mi = 0; mi < 4; ++mi)
#pragma unroll
                for (int r = 0; r < 4; ++r) mt = fmaxf(mt, sc[mi][ni][r]);
            mt = fmaxf(mt, __shfl_xor(mt, 16));
            mt = fmaxf(mt, __shfl_xor(mt, 32));
            float mnew = fmaxf(m_run[ni], mt);
            float co = __expf(m_run[ni] - mnew);
            m_run[ni] = mnew;
            float ps = 0.f;
            int q = ni * 16 + c;
#pragma unroll
            for (int mi = 0; mi < 4; ++mi) {
                float p0 = __expf(sc[mi][ni][0] - mnew);
                float p1 = __expf(sc[mi][ni][1] - mnew);
                float p2 = __expf(sc[mi][ni][2] - mnew);
                float p3 = __expf(sc[mi][ni][3] - mnew);
                ps += (p0 + p1) + (p2 + p3);
                *(unsigned long long*)(Pw + q * 128 + ((2 * (mi * 16 + g * 4)) ^ ((q & 7) << 4))) =
                    pack4bf(p0, p1, p2, p3);
            }
            ps += __shfl_xor(ps, 16);
            ps += __shfl_xor(ps, 32);
            l_run[ni] = l_run[ni] * co + ps;
            if (g == 0) corw[q] = co;
        }
        LDS_FENCE();                          // P + corr writes must precede reads below
#pragma unroll
        for (int mf = 0; mf < 2; ++mf) {
            float cr0 = corw[mf * 16 + g * 4 + 0];
            float cr1 = corw[mf * 16 + g * 4 + 1];
            float cr2 = corw[mf * 16 + g * 4 + 2];
            float cr3 = corw[mf * 16 + g * 4 + 3];
#pragma unroll
            for (int nf = 0; nf < 4; ++nf) {
                acc[mf][nf][0] *= cr0; acc[mf][nf][1] *= cr1;
                acc[mf][nf][2] *= cr2; acc[mf][nf][3] *= cr3;
            }
        }
        bf16x8 PA[2][2], VBf[4][2];
#pragma unroll
        for (int mf = 0; mf < 2; ++mf)
#pragma unroll
            for (int ks = 0; ks < 2; ++ks) {
                int q = mf * 16 + c;
                PA[mf][ks] = *(const bf16x8*)(Pw + q * 128 + ((ks * 64 + g * 16) ^ ((q & 7) << 4)));
            }
#pragma unroll
        for (int nf = 0; nf < 4; ++nf)
#pragma unroll
            for (int ks = 0; ks < 2; ++ks) {
                int d = nf * 16 + c;
                VBf[nf][ks] = *(const bf16x8*)(vb + d * 128 + ((ks * 64 + g * 16) ^ (((d >> 2) & 7) << 4)));
            }
#pragma unroll
        for (int mf = 0; mf < 2; ++mf)
#pragma unroll
            for (int nf = 0; nf < 4; ++nf) {
                acc[mf][nf] = __builtin_amdgcn_mfma_f32_16x16x32_bf16(PA[mf][0], VBf[nf][0], acc[mf][nf], 0, 0, 0);
                acc[mf][nf] = __builtin_amdgcn_mfma_f32_16x16x32_bf16(PA[mf][1], VBf[nf][1], acc[mf][nf], 0, 0, 0);
            }
        __syncthreads();
    }

    if (g == 0) { corw[c] = 1.f / l_run[0]; corw[16 + c] = 1.f / l_run[1]; }
    LDS_FENCE();
#pragma unroll
    for (int mf = 0; mf < 2; ++mf) {
        float iv[4];
#pragma unroll
        for (int r = 0; r < 4; ++r) iv[r] = corw[mf * 16 + g * 4 + r];
#pragma unroll
        for (int r = 0; r < 4; ++r) {
            size_t row = (size_t)b * S + (size_t)wi * WIN + qt * 128 + wv * 32 + mf * 16 + g * 4 + r;
#pragma unroll
            for (int nf = 0; nf < 4; ++nf) {
                int col = h * HD + nf * 16 + c;
                float o = acc[mf][nf][r] * iv[r];
                local[row * D + col] = o;
                local_bf[row * D + col] = f2bf(o);
            }
        }
    }
}

// ---------------------------------------------------------------- kernel 3a: conv as split-K GEMM
__launch_bounds__(256)
__global__ void k_conv_part(const float* __restrict__ xe, const float* __restrict__ convw,
                            float* __restrict__ part) {
    int bid = blockIdx.x;
    int nt = bid & 15, mt = (bid >> 4) & 3, kc = bid >> 6;
    __shared__ float As[32][68];
    __shared__ float Bs[32][68];
    int t = threadIdx.x, tx = t & 15, ty = t >> 4;
    float acc[4][4] = {};
    for (int k0 = 0; k0 < 1024; k0 += 32) {
#pragma unroll
        for (int p = 0; p < 2; ++p) {
            int fidx = t + 256 * p;
            int am = fidx >> 3, ak4 = fidx & 7;
            int bg = mt * 64 + am, b = bg >> 6, g = bg & 63;
            float4 v = *(const float4*)(xe + ((size_t)b * S + 4 * g + kc) * D + k0 + ak4 * 4);
            As[ak4*4+0][am] = v.x; As[ak4*4+1][am] = v.y;
            As[ak4*4+2][am] = v.z; As[ak4*4+3][am] = v.w;
        }
#pragma unroll
        for (int p = 0; p < 8; ++p) {
            int bk = t & 31, bn = (t >> 5) + 8 * p;
            Bs[bk][bn] = convw[(size_t)(nt * 64 + bn) * 4096 + (size_t)(k0 + bk) * 4 + kc];
        }
        __syncthreads();
#pragma unroll
        for (int kk = 0; kk < 32; ++kk) {
            float a[4], bb[4];
            *(float4*)a  = *(const float4*)(&As[kk][ty * 4]);
            *(float4*)bb = *(const float4*)(&Bs[kk][tx * 4]);
#pragma unroll
            for (int i = 0; i < 4; ++i)
#pragma unroll
                for (int j = 0; j < 4; ++j)
                    acc[i][j] = fmaf(a[i], bb[j], acc[i][j]);
        }
        __syncthreads();
    }
#pragma unroll
    for (int i = 0; i < 4; ++i) {
        size_t off = ((size_t)kc * 256 + mt * 64 + ty * 4 + i) * 1024 + nt * 64 + tx * 4;
        *(float4*)(part + off) = make_float4(acc[i][0], acc[i][1], acc[i][2], acc[i][3]);
    }
}

// ---------------------------------------------------------------- kernel 3b: assemble gt
__global__ void k_gt(const float* __restrict__ part, const float* __restrict__ convb,
                     const float* __restrict__ gmem, float* __restrict__ gt) {
    int f = blockIdx.x * blockDim.x + threadIdx.x;
    int n4  = f & 255;
    int tok = (f >> 8) & 127;
    int b   = f >> 15;
    float4 v;
    if (tok < 64) {
        v = ((const float4*)convb)[n4];
#pragma unroll
        for (int kc = 0; kc < 4; ++kc) {
            float4 p = ((const float4*)part)[((size_t)kc * 256 + b * 64 + tok) * 256 + n4];
            v.x += p.x; v.y += p.y; v.z += p.z; v.w += p.w;
        }
    } else {
        v = ((const float4*)gmem)[(size_t)(tok - 64) * 256 + n4];
    }
    ((float4*)gt)[f] = v;
}

// ---------------------------------------------------------------- kernel 4: MFMA global attention
// Literal clone of k_winattn control flow: runtime kt-loop (2 iters), in-loop dbuf
// staging, __syncthreads() at each iteration end. K/V = 128 gt tokens (head slice).
// grid: (qt=S/128, h, b) = 2048 blocks.
__launch_bounds__(256)
__global__ void k_globattn(const float* __restrict__ xe, const float* __restrict__ gt,
                           float* __restrict__ glob, unsigned short* __restrict__ glob_bf) {
    int blk = blockIdx.x;
    int qt = blk & 31, h = (blk >> 5) & 15, b = blk >> 9;

    __shared__ __align__(16) unsigned char lds[66048];
    unsigned char* Qs = lds;
    unsigned char* Kb = lds + 16384;
    unsigned char* Vb = lds + 32768;
    unsigned char* Pb = lds + 49152;
    float* corr = (float*)(lds + 65536);

    const int t = threadIdx.x;
    const int wv = t >> 6, l = t & 63;
    const int g = l >> 4, c = l & 15;

    const float* qbase  = xe + ((size_t)b * S + (size_t)qt * 128) * D + h * HD;
    const float* kvbase = gt + (size_t)b * G2 * D + h * HD;

#pragma unroll
    for (int p = 0; p < 8; ++p) {
        int i = t + 256 * p;
        int q = i >> 4, c4 = i & 15;
        float4 v = *(const float4*)(qbase + (size_t)q * D + c4 * 4);
        *(unsigned long long*)(Qs + q * 128 + ((c4 * 8) ^ ((q & 7) << 4))) =
            pack4bf(v.x * SCALE, v.y * SCALE, v.z * SCALE, v.w * SCALE);
    }

    auto stage_kv = [&](int kt, int bb) {
        unsigned char* kb = Kb + bb * 8192;
        unsigned char* vb = Vb + bb * 8192;
#pragma unroll
        for (int p = 0; p < 4; ++p) {
            int i = t + 256 * p;
            int key = i >> 4, c4 = i & 15;
            float4 v = *(const float4*)(kvbase + (size_t)(kt * 64 + key) * D + c4 * 4);
            *(unsigned long long*)(kb + key * 128 + ((c4 * 8) ^ ((key & 7) << 4))) =
                pack4bf(v.x, v.y, v.z, v.w);
            int swz = (c4 & 7) << 4;
            int d0 = c4 * 4;
            *(unsigned short*)(vb + (d0 + 0) * 128 + ((key * 2) ^ swz)) = f2bf(v.x);
            *(unsigned short*)(vb + (d0 + 1) * 128 + ((key * 2) ^ swz)) = f2bf(v.y);
            *(unsigned short*)(vb + (d0 + 2) * 128 + ((key * 2) ^ swz)) = f2bf(v.z);
            *(unsigned short*)(vb + (d0 + 3) * 128 + ((key * 2) ^ swz)) = f2bf(v.w);
        }
    };

    stage_kv(0, 0);
    __syncthreads();

    bf16x8 QB[2][2];
#pragma unroll
    for (int ni = 0; ni < 2; ++ni)
#pragma unroll
        for (int ds = 0; ds < 2; ++ds) {
            int q = wv * 32 + ni * 16 + c;
            QB[ni][ds] = *(const bf16x8*)(Qs + q * 128 + ((ds * 64 + g * 16) ^ ((q & 7) << 4)));
        }

    float m_run[2] = {-1e30f, -1e30f};
    float l_run[2] = {0.f, 0.f};
    f32x4 acc[2][4] = {};
    unsigned char* Pw = Pb + wv * 4096;
    float* corw = corr + wv * 32;

    for (int kt = 0; kt < 2; ++kt) {
        int bb = kt & 1;
        if (kt < 1) stage_kv(kt + 1, bb ^ 1);

        unsigned char* kb = Kb + bb * 8192;
        unsigned char* vb = Vb + bb * 8192;
        bf16x8 KA[4][2];
#pragma unroll
        for (int mi = 0; mi < 4; ++mi)
#pragma unroll
            for (int ds = 0; ds < 2; ++ds) {
                int key = mi * 16 + c;
                KA[mi][ds] = *(const bf16x8*)(kb + key * 128 + ((ds * 64 + g * 16) ^ ((key & 7) << 4)));
            }
        f32x4 sc[4][2] = {};
#pragma unroll
        for (int mi = 0; mi < 4; ++mi)
#pragma unroll
            for (int ni = 0; ni < 2; ++ni) {
                sc[mi][ni] = __builtin_amdgcn_mfma_f32_16x16x32_bf16(KA[mi][0], QB[ni][0], sc[mi][ni], 0, 0, 0);
                sc[mi][ni] = __builtin_amdgcn_mfma_f32_16x16x32_bf16(KA[mi][1], QB[ni][1], sc[mi][ni], 0, 0, 0);
            }
#pragma unroll
        for (int ni = 0; ni < 2; ++ni) {
            float mt = sc[0][ni][0];
#pragma unroll
            for (int mi = 0; mi < 4; ++mi)
#pragma unroll
                for (int r = 0; r < 4; ++r) mt = fmaxf(mt, sc[mi][ni][r]);
            mt = fmaxf(mt, __shfl_xor(mt, 16));
            mt = fmaxf(mt, __shfl_xor(mt, 32));
            float mnew = fmaxf(m_run[ni], mt);
            float co = __expf(m_run[ni] - mnew);
            m_run[ni] = mnew;
            float ps = 0.f;
            int q = ni * 16 + c;
#pragma unroll
            for (int mi = 0; mi < 4; ++mi) {
                float p0 = __expf(sc[mi][ni][0] - mnew);
                float p1 = __expf(sc[mi][ni][1] - mnew);
                float p2 = __expf(sc[mi][ni][2] - mnew);
                float p3 = __expf(sc[mi][ni][3] - mnew);
                ps += (p0 + p1) + (p2 + p3);
                *(unsigned long long*)(Pw + q * 128 + ((2 * (mi * 16 + g * 4)) ^ ((q & 7) << 4))) =
                    pack4bf(p0, p1, p2, p3);
            }
            ps += __shfl_xor(ps, 16);
            ps += __shfl_xor(ps, 32);
            l_run[ni] = l_run[ni] * co + ps;
            if (g == 0) corw[q] = co;
        }
        LDS_FENCE();                          // P + corr writes must precede reads below
#pragma unroll
        for (int mf = 0; mf < 2; ++mf) {
            float cr0 = corw[mf * 16 + g * 4 + 0];
            float cr1 = corw[mf * 16 + g * 4 + 1];
            float cr2 = corw[mf * 16 + g * 4 + 2];
            float cr3 = corw[mf * 16 + g * 4 + 3];
#pragma unroll
            for (int nf = 0; nf < 4; ++nf) {
                acc[mf][nf][0] *= cr0; acc[mf][nf][1] *= cr1;
                acc[mf][nf][2] *= cr2; acc[mf][nf][3] *= cr3;
            }
        }
        bf16x8 PA[2][2], VBf[4][2];
#pragma unroll
        for (int mf = 0; mf < 2; ++mf)
#pragma unroll
            for (int ks = 0; ks < 2; ++ks) {
                int q = mf * 16 + c;
                PA[mf][ks] = *(const bf16x8*)(Pw + q * 128 + ((ks * 64 + g * 16) ^ ((q & 7) << 4)));
            }
#pragma unroll
        for (int nf = 0; nf < 4; ++nf)
#pragma unroll
            for (int ks = 0; ks < 2; ++ks) {
                int d = nf * 16 + c;
                VBf[nf][ks] = *(const bf16x8*)(vb + d * 128 + ((ks * 64 + g * 16) ^ (((d >> 2) & 7) << 4)));
            }
#pragma unroll
        for (int mf = 0; mf < 2; ++mf)
#pragma unroll
            for (int nf = 0; nf < 4; ++nf) {
                acc[mf][nf] = __builtin_amdgcn_mfma_f32_16x16x32_bf16(PA[mf][0], VBf[nf][0], acc[mf][nf], 0, 0, 0);
                acc[mf][nf] = __builtin_amdgcn_mfma_f32_16x16x32_bf16(PA[mf][1], VBf[nf][1], acc[mf][nf], 0, 0, 0);
            }
        __syncthreads();
    }

    if (g == 0) { corw[c] = 1.f / l_run[0]; corw[16 + c] = 1.f / l_run[1]; }
    LDS_FENCE();
#pragma unroll
    for (int mf = 0; mf < 2; ++mf) {
        float iv[4];
#pragma unroll
        for (int r = 0; r < 4; ++r) iv[r] = corw[mf * 16 + g * 4 + r];
#pragma unroll
        for (int r = 0; r < 4; ++r) {
            size_t row = (size_t)b * S + (size_t)qt * 128 + wv * 32 + mf * 16 + g * 4 + r;
#pragma unroll
            for (int nf = 0; nf < 4; ++nf) {
                int col = h * HD + nf * 16 + c;
                float o = acc[mf][nf][r] * iv[r];
                glob[row * D + col] = o;
                glob_bf[row * D + col] = f2bf(o);
            }
        }
    }
}

// ---------------------------------------------------------------- kernels 5/6: bf16 MFMA GEMMs
template <int MODE>
__launch_bounds__(256)
__global__ void k_mgemm(const unsigned short* __restrict__ A0,
                        const unsigned short* __restrict__ A1,
                        const unsigned short* __restrict__ BT,
                        const float* __restrict__ bias,
                        const float* __restrict__ localf,
                        const float* __restrict__ globf,
                        void* __restrict__ Cout) {
    constexpr int K = (MODE == 0) ? 2048 : 1024;
    __shared__ __align__(16) unsigned short As[128 * 32];
    __shared__ __align__(16) unsigned short Bs[128 * 32];
    const int t = threadIdx.x;
    const int wv = t >> 6, ln = t & 63;
    const int lrow = ln & 15, lk = ln >> 4;
    const int wr = wv >> 1, wc = wv & 1;
    const int bn = blockIdx.x * 128, bm = blockIdx.y * 128;
    const int arow = ln >> 2;
    const int acol8 = (ln & 3) * 8;

    f32x4 acc[4][4] = {};

    for (int k0 = 0; k0 < K; k0 += 32) {
        const unsigned short* Ab;
        int kloc;
        if constexpr (MODE == 0) { Ab = (k0 < 1024) ? A0 : A1; kloc = k0 & 1023; }
        else                     { Ab = A0; kloc = k0; }
        gload16(Ab + (size_t)(bm + wv * 32 + arow) * 1024 + kloc + acol8,
                As + wv * 32 * 32);
        gload16(Ab + (size_t)(bm + wv * 32 + 16 + arow) * 1024 + kloc + acol8,
                As + wv * 32 * 32 + 16 * 32);
        gload16(BT + (size_t)(bn + wv * 32 + arow) * K + k0 + acol8,
                Bs + wv * 32 * 32);
        gload16(BT + (size_t)(bn + wv * 32 + 16 + arow) * K + k0 + acol8,
                Bs + wv * 32 * 32 + 16 * 32);
        __syncthreads();
        bf16x8 af[4], bfr[4];
#pragma unroll
        for (int m = 0; m < 4; ++m)
            af[m] = *(const bf16x8*)(As + (wr * 64 + m * 16 + lrow) * 32 + lk * 8);
#pragma unroll
        for (int n = 0; n < 4; ++n)
            bfr[n] = *(const bf16x8*)(Bs + (wc * 64 + n * 16 + lrow) * 32 + lk * 8);
#pragma unroll
        for (int m = 0; m < 4; ++m)
#pragma unroll
            for (int n = 0; n < 4; ++n)
                acc[m][n] = __builtin_amdgcn_mfma_f32_16x16x32_bf16(af[m], bfr[n], acc[m][n], 0, 0, 0);
        __syncthreads();
    }

#pragma unroll
    for (int m = 0; m < 4; ++m) {
#pragma unroll
        for (int n = 0; n < 4; ++n) {
            int col = bn + wc * 64 + n * 16 + lrow;
            float bv = bias[col];
#pragma unroll
            for (int r = 0; r < 4; ++r) {
                int row = bm + wr * 64 + m * 16 + lk * 4 + r;
                size_t off = (size_t)row * 1024 + col;
                float v = acc[m][n][r] + bv;
                if constexpr (MODE == 0) {
                    float mixv = 1.f / (1.f + __expf(-v));
                    float o = mixv * localf[off] + (1.f - mixv) * globf[off];
                    ((unsigned short*)Cout)[off] = f2bf(o);
                } else {
                    ((float*)Cout)[off] = v;
                }
            }
        }
    }
}

// ---------------------------------------------------------------- launch
extern "C" void kernel_launch(void* const* d_in, const int* in_sizes, int n_in,
                              void* d_out, int out_size, void* d_ws, size_t ws_size,
                              hipStream_t stream) {
    (void)in_sizes; (void)n_in; (void)out_size; (void)ws_size;
    const float* x     = (const float*)d_in[0];
    const float* pos   = (const float*)d_in[1];
    const float* gmem  = (const float*)d_in[2];
    const float* convw = (const float*)d_in[3];
    const float* convb = (const float*)d_in[4];
    const float* gatew = (const float*)d_in[5];
    const float* gateb = (const float*)d_in[6];
    const float* outw  = (const float*)d_in[7];
    const float* outb  = (const float*)d_in[8];

    float* ws = (float*)d_ws;
    float* xe    = ws;                                    // 16,777,216 f
    float* globf = xe + 16777216;                         // 16,777,216 f
    float* gt    = globf + 16777216;                      //    524,288 f
    float* part  = gt + 524288;                           //  1,048,576 f
    unsigned short* local_bf = (unsigned short*)(part + 1048576);  // 16M u16
    unsigned short* glob_bf  = local_bf + 16777216;                // 16M u16
    unsigned short* wTg      = glob_bf + 16777216;                 //  2M u16
    unsigned short* wTo      = wTg + 2097152;                      //  1M u16
    unsigned short* mixed_bf = (unsigned short*)xe;       // alias: xe dead after globattn
    float* localf = (float*)d_out;                        // overwritten by final GEMM

    k_posadd  <<<16384, 256, 0, stream>>>(x, pos, xe);
    k_wtrans<2048><<<dim3(64, 32), 256, 0, stream>>>(gatew, wTg);
    k_wtrans<1024><<<dim3(32, 32), 256, 0, stream>>>(outw, wTo);
    k_winattn <<<B * NW * H * 4, 256, 0, stream>>>(xe, localf, local_bf);
    k_conv_part<<<256, 256, 0, stream>>>(xe, convw, part);
    k_gt      <<<512, 256, 0, stream>>>(part, convb, gmem, gt);
    k_globattn<<<B * H * (S / 128), 256, 0, stream>>>(xe, gt, globf, glob_bf);
    k_mgemm<0><<<dim3(8, 128), 256, 0, stream>>>(local_bf, glob_bf, wTg, gateb,
                                                 localf, globf, mixed_bf);
    k_mgemm<1><<<dim3(8, 128), 256, 0, stream>>>(mixed_bf, nullptr, wTo, outb,
                                                 nullptr, nullptr, d_out);
}

// Round 8
// 515.314 us; speedup vs baseline: 4.1474x; 1.0985x over previous
//
#include <hip/hip_runtime.h>
#include <math.h>

#define B 4
#define S 4096
#define D 1024
#define H 16
#define HD 64
#define WIN 512
#define NW 8
#define G 64
#define G2 128
#define SCALE 0.125f

typedef __attribute__((ext_vector_type(8))) short bf16x8;
typedef __attribute__((ext_vector_type(4))) float f32x4;

__device__ inline unsigned short f2bf(float f) {
    unsigned u = __builtin_bit_cast(unsigned, f);
    return (unsigned short)((u + 0x7FFFu + ((u >> 16) & 1u)) >> 16);
}

__device__ inline float bf2f(unsigned short u) {
    return __builtin_bit_cast(float, (unsigned)u << 16);
}

__device__ inline unsigned long long pack4bf(float a, float b, float c, float d) {
    return (unsigned long long)f2bf(a) | ((unsigned long long)f2bf(b) << 16) |
           ((unsigned long long)f2bf(c) << 32) | ((unsigned long long)f2bf(d) << 48);
}

__device__ inline void gload16(const void* g, void* l) {
    __builtin_amdgcn_global_load_lds(
        (const __attribute__((address_space(1))) unsigned*)g,
        (__attribute__((address_space(3))) unsigned*)l, 16, 0, 0);
}

// compiler-only ordering fence for LDS write->read hand-offs (HW DS is in-order per wave)
#define LDS_FENCE() asm volatile("" ::: "memory")

// ---------------------------------------------------------------- kernel 1: x + pos_emb
__global__ void k_posadd(const float* __restrict__ x, const float* __restrict__ pos,
                         float* __restrict__ xe) {
    int i = blockIdx.x * blockDim.x + threadIdx.x;
    float4 xv = ((const float4*)x)[i];
    int e = i & (S * D / 4 - 1);
    float4 pv = ((const float4*)pos)[e];
    xv.x += pv.x; xv.y += pv.y; xv.z += pv.z; xv.w += pv.w;
    ((float4*)xe)[i] = xv;
}

// ---------------------------------------------------------------- weight transpose + bf16
template <int KD>
__global__ void k_wtrans(const float* __restrict__ w, unsigned short* __restrict__ wT) {
    __shared__ float tile[32][33];
    int k0 = blockIdx.x * 32, n0 = blockIdx.y * 32;
    int tx = threadIdx.x & 31, ty = threadIdx.x >> 5;
#pragma unroll
    for (int i = 0; i < 4; ++i)
        tile[ty + 8 * i][tx] = w[(size_t)(k0 + ty + 8 * i) * 1024 + n0 + tx];
    __syncthreads();
#pragma unroll
    for (int i = 0; i < 4; ++i)
        wT[(size_t)(n0 + ty + 8 * i) * KD + k0 + tx] = f2bf(tile[tx][ty + 8 * i]);
}

// ---------------------------------------------------------------- kernel 2: MFMA window attention
__launch_bounds__(256)
__global__ void k_winattn(const float* __restrict__ xe, unsigned short* __restrict__ local_bf) {
    int blk = blockIdx.x;
    int qt = blk & 3, h = (blk >> 2) & 15, wi = (blk >> 6) & 7, b = blk >> 9;

    __shared__ __align__(16) unsigned char lds[66048];
    unsigned char* Qs = lds;                 // [128][64] bf16, swz by q       16 KB
    unsigned char* Kb = lds + 16384;         // 2x [64][64] bf16, swz by key   16 KB
    unsigned char* Vb = lds + 32768;         // 2x [64 d][64 key] bf16, swz d>>2 16 KB
    unsigned char* Pb = lds + 49152;         // 4x [32][64] bf16, swz by q     16 KB
    float* corr = (float*)(lds + 65536);     // 4 x 32 floats

    const int t = threadIdx.x;
    const int wv = t >> 6, l = t & 63;
    const int g = l >> 4, c = l & 15;

    const float* wbase = xe + ((size_t)b * S + (size_t)wi * WIN) * D + h * HD;

#pragma unroll
    for (int p = 0; p < 8; ++p) {
        int i = t + 256 * p;
        int q = i >> 4, c4 = i & 15;
        float4 v = *(const float4*)(wbase + (size_t)(qt * 128 + q) * D + c4 * 4);
        *(unsigned long long*)(Qs + q * 128 + ((c4 * 8) ^ ((q & 7) << 4))) =
            pack4bf(v.x * SCALE, v.y * SCALE, v.z * SCALE, v.w * SCALE);
    }

    auto stage_kv = [&](int kt, int bb) {
        unsigned char* kb = Kb + bb * 8192;
        unsigned char* vb = Vb + bb * 8192;
#pragma unroll
        for (int p = 0; p < 4; ++p) {
            int i = t + 256 * p;
            int key = i >> 4, c4 = i & 15;
            float4 v = *(const float4*)(wbase + (size_t)(kt * 64 + key) * D + c4 * 4);
            *(unsigned long long*)(kb + key * 128 + ((c4 * 8) ^ ((key & 7) << 4))) =
                pack4bf(v.x, v.y, v.z, v.w);
            int swz = (c4 & 7) << 4;
            int d0 = c4 * 4;
            *(unsigned short*)(vb + (d0 + 0) * 128 + ((key * 2) ^ swz)) = f2bf(v.x);
            *(unsigned short*)(vb + (d0 + 1) * 128 + ((key * 2) ^ swz)) = f2bf(v.y);
            *(unsigned short*)(vb + (d0 + 2) * 128 + ((key * 2) ^ swz)) = f2bf(v.z);
            *(unsigned short*)(vb + (d0 + 3) * 128 + ((key * 2) ^ swz)) = f2bf(v.w);
        }
    };

    stage_kv(0, 0);
    __syncthreads();

    bf16x8 QB[2][2];
#pragma unroll
    for (int ni = 0; ni < 2; ++ni)
#pragma unroll
        for (int ds = 0; ds < 2; ++ds) {
            int q = wv * 32 + ni * 16 + c;
            QB[ni][ds] = *(const bf16x8*)(Qs + q * 128 + ((ds * 64 + g * 16) ^ ((q & 7) << 4)));
        }

    float m_run[2] = {-1e30f, -1e30f};
    float l_run[2] = {0.f, 0.f};
    f32x4 acc[2][4] = {};
    unsigned char* Pw = Pb + wv * 4096;
    float* corw = corr + wv * 32;

    for (int kt = 0; kt < 8; ++kt) {
        int bb = kt & 1;
        if (kt < 7) stage_kv(kt + 1, bb ^ 1);

        unsigned char* kb = Kb + bb * 8192;
        unsigned char* vb = Vb + bb * 8192;
        bf16x8 KA[4][2];
#pragma unroll
        for (int mi = 0; mi < 4; ++mi)
#pragma unroll
            for (int ds = 0; ds < 2; ++ds) {
                int key = mi * 16 + c;
                KA[mi][ds] = *(const bf16x8*)(kb + key * 128 + ((ds * 64 + g * 16) ^ ((key & 7) << 4)));
            }
        f32x4 sc[4][2] = {};
#pragma unroll
        for (int mi = 0; mi < 4; ++mi)
#pragma unroll
            for (int ni = 0; ni < 2; ++ni) {
                sc[mi][ni] = __builtin_amdgcn_mfma_f32_16x16x32_bf16(KA[mi][0], QB[ni][0], sc[mi][ni], 0, 0, 0);
                sc[mi][ni] = __builtin_amdgcn_mfma_f32_16x16x32_bf16(KA[mi][1], QB[ni][1], sc[mi][ni], 0, 0, 0);
            }
#pragma unroll
        for (int ni = 0; ni < 2; ++ni) {
            float mt = sc[0][ni][0];
#pragma unroll
            for (int mi = 0; mi < 4; ++mi)
#pragma unroll
                for (int r = 0; r < 4; ++r) mt = fmaxf(mt, sc[mi][ni][r]);
            mt = fmaxf(mt, __shfl_xor(mt, 16));
            mt = fmaxf(mt, __shfl_xor(mt, 32));
            float mnew = fmaxf(m_run[ni], mt);
            float co = __expf(m_run[ni] - mnew);
            m_run[ni] = mnew;
            float ps = 0.f;
            int q = ni * 16 + c;
#pragma unroll
            for (int mi = 0; mi < 4; ++mi) {
                float p0 = __expf(sc[mi][ni][0] - mnew);
                float p1 = __expf(sc[mi][ni][1] - mnew);
                float p2 = __expf(sc[mi][ni][2] - mnew);
                float p3 = __expf(sc[mi][ni][3] - mnew);
                ps += (p0 + p1) + (p2 + p3);
                *(unsigned long long*)(Pw + q * 128 + ((2 * (mi * 16 + g * 4)) ^ ((q & 7) << 4))) =
                    pack4bf(p0, p1, p2, p3);
            }
            ps += __shfl_xor(ps, 16);
            ps += __shfl_xor(ps, 32);
            l_run[ni] = l_run[ni] * co + ps;
            if (g == 0) corw[q] = co;
        }
        LDS_FENCE();
#pragma unroll
        for (int mf = 0; mf < 2; ++mf) {
            float cr0 = corw[mf * 16 + g * 4 + 0];
            float cr1 = corw[mf * 16 + g * 4 + 1];
            float cr2 = corw[mf * 16 + g * 4 + 2];
            float cr3 = corw[mf * 16 + g * 4 + 3];
#pragma unroll
            for (int nf = 0; nf < 4; ++nf) {
                acc[mf][nf][0] *= cr0; acc[mf][nf][1] *= cr1;
                acc[mf][nf][2] *= cr2; acc[mf][nf][3] *= cr3;
            }
        }
        bf16x8 PA[2][2], VBf[4][2];
#pragma unroll
        for (int mf = 0; mf < 2; ++mf)
#pragma unroll
            for (int ks = 0; ks < 2; ++ks) {
                int q = mf * 16 + c;
                PA[mf][ks] = *(const bf16x8*)(Pw + q * 128 + ((ks * 64 + g * 16) ^ ((q & 7) << 4)));
            }
#pragma unroll
        for (int nf = 0; nf < 4; ++nf)
#pragma unroll
            for (int ks = 0; ks < 2; ++ks) {
                int d = nf * 16 + c;
                VBf[nf][ks] = *(const bf16x8*)(vb + d * 128 + ((ks * 64 + g * 16) ^ (((d >> 2) & 7) << 4)));
            }
#pragma unroll
        for (int mf = 0; mf < 2; ++mf)
#pragma unroll
            for (int nf = 0; nf < 4; ++nf) {
                acc[mf][nf] = __builtin_amdgcn_mfma_f32_16x16x32_bf16(PA[mf][0], VBf[nf][0], acc[mf][nf], 0, 0, 0);
                acc[mf][nf] = __builtin_amdgcn_mfma_f32_16x16x32_bf16(PA[mf][1], VBf[nf][1], acc[mf][nf], 0, 0, 0);
            }
        __syncthreads();
    }

    if (g == 0) { corw[c] = 1.f / l_run[0]; corw[16 + c] = 1.f / l_run[1]; }
    LDS_FENCE();
#pragma unroll
    for (int mf = 0; mf < 2; ++mf) {
        float iv[4];
#pragma unroll
        for (int r = 0; r < 4; ++r) iv[r] = corw[mf * 16 + g * 4 + r];
#pragma unroll
        for (int r = 0; r < 4; ++r) {
            size_t row = (size_t)b * S + (size_t)wi * WIN + qt * 128 + wv * 32 + mf * 16 + g * 4 + r;
#pragma unroll
            for (int nf = 0; nf < 4; ++nf) {
                int col = h * HD + nf * 16 + c;
                local_bf[row * D + col] = f2bf(acc[mf][nf][r] * iv[r]);
            }
        }
    }
}

// ---------------------------------------------------------------- kernel 3a: conv as split-K GEMM
__launch_bounds__(256)
__global__ void k_conv_part(const float* __restrict__ xe, const float* __restrict__ convw,
                            float* __restrict__ part) {
    int bid = blockIdx.x;
    int nt = bid & 15, mt = (bid >> 4) & 3, kc = bid >> 6;
    __shared__ float As[32][68];
    __shared__ float Bs[32][68];
    int t = threadIdx.x, tx = t & 15, ty = t >> 4;
    float acc[4][4] = {};
    for (int k0 = 0; k0 < 1024; k0 += 32) {
#pragma unroll
        for (int p = 0; p < 2; ++p) {
            int fidx = t + 256 * p;
            int am = fidx >> 3, ak4 = fidx & 7;
            int bg = mt * 64 + am, b = bg >> 6, g = bg & 63;
            float4 v = *(const float4*)(xe + ((size_t)b * S + 4 * g + kc) * D + k0 + ak4 * 4);
            As[ak4*4+0][am] = v.x; As[ak4*4+1][am] = v.y;
            As[ak4*4+2][am] = v.z; As[ak4*4+3][am] = v.w;
        }
#pragma unroll
        for (int p = 0; p < 8; ++p) {
            int bk = t & 31, bn = (t >> 5) + 8 * p;
            Bs[bk][bn] = convw[(size_t)(nt * 64 + bn) * 4096 + (size_t)(k0 + bk) * 4 + kc];
        }
        __syncthreads();
#pragma unroll
        for (int kk = 0; kk < 32; ++kk) {
            float a[4], bb[4];
            *(float4*)a  = *(const float4*)(&As[kk][ty * 4]);
            *(float4*)bb = *(const float4*)(&Bs[kk][tx * 4]);
#pragma unroll
            for (int i = 0; i < 4; ++i)
#pragma unroll
                for (int j = 0; j < 4; ++j)
                    acc[i][j] = fmaf(a[i], bb[j], acc[i][j]);
        }
        __syncthreads();
    }
#pragma unroll
    for (int i = 0; i < 4; ++i) {
        size_t off = ((size_t)kc * 256 + mt * 64 + ty * 4 + i) * 1024 + nt * 64 + tx * 4;
        *(float4*)(part + off) = make_float4(acc[i][0], acc[i][1], acc[i][2], acc[i][3]);
    }
}

// ---------------------------------------------------------------- kernel 3b: assemble gt
__global__ void k_gt(const float* __restrict__ part, const float* __restrict__ convb,
                     const float* __restrict__ gmem, float* __restrict__ gt) {
    int f = blockIdx.x * blockDim.x + threadIdx.x;
    int n4  = f & 255;
    int tok = (f >> 8) & 127;
    int b   = f >> 15;
    float4 v;
    if (tok < 64) {
        v = ((const float4*)convb)[n4];
#pragma unroll
        for (int kc = 0; kc < 4; ++kc) {
            float4 p = ((const float4*)part)[((size_t)kc * 256 + b * 64 + tok) * 256 + n4];
            v.x += p.x; v.y += p.y; v.z += p.z; v.w += p.w;
        }
    } else {
        v = ((const float4*)gmem)[(size_t)(tok - 64) * 256 + n4];
    }
    ((float4*)gt)[f] = v;
}

// ---------------------------------------------------------------- kernel 4: MFMA global attention
__launch_bounds__(256)
__global__ void k_globattn(const float* __restrict__ xe, const float* __restrict__ gt,
                           unsigned short* __restrict__ glob_bf) {
    int blk = blockIdx.x;
    int qt = blk & 31, h = (blk >> 5) & 15, b = blk >> 9;

    __shared__ __align__(16) unsigned char lds[66048];
    unsigned char* Qs = lds;
    unsigned char* Kb = lds + 16384;
    unsigned char* Vb = lds + 32768;
    unsigned char* Pb = lds + 49152;
    float* corr = (float*)(lds + 65536);

    const int t = threadIdx.x;
    const int wv = t >> 6, l = t & 63;
    const int g = l >> 4, c = l & 15;

    const float* qbase  = xe + ((size_t)b * S + (size_t)qt * 128) * D + h * HD;
    const float* kvbase = gt + (size_t)b * G2 * D + h * HD;

#pragma unroll
    for (int p = 0; p < 8; ++p) {
        int i = t + 256 * p;
        int q = i >> 4, c4 = i & 15;
        float4 v = *(const float4*)(qbase + (size_t)q * D + c4 * 4);
        *(unsigned long long*)(Qs + q * 128 + ((c4 * 8) ^ ((q & 7) << 4))) =
            pack4bf(v.x * SCALE, v.y * SCALE, v.z * SCALE, v.w * SCALE);
    }

    auto stage_kv = [&](int kt, int bb) {
        unsigned char* kb = Kb + bb * 8192;
        unsigned char* vb = Vb + bb * 8192;
#pragma unroll
        for (int p = 0; p < 4; ++p) {
            int i = t + 256 * p;
            int key = i >> 4, c4 = i & 15;
            float4 v = *(const float4*)(kvbase + (size_t)(kt * 64 + key) * D + c4 * 4);
            *(unsigned long long*)(kb + key * 128 + ((c4 * 8) ^ ((key & 7) << 4))) =
                pack4bf(v.x, v.y, v.z, v.w);
            int swz = (c4 & 7) << 4;
            int d0 = c4 * 4;
            *(unsigned short*)(vb + (d0 + 0) * 128 + ((key * 2) ^ swz)) = f2bf(v.x);
            *(unsigned short*)(vb + (d0 + 1) * 128 + ((key * 2) ^ swz)) = f2bf(v.y);
            *(unsigned short*)(vb + (d0 + 2) * 128 + ((key * 2) ^ swz)) = f2bf(v.z);
            *(unsigned short*)(vb + (d0 + 3) * 128 + ((key * 2) ^ swz)) = f2bf(v.w);
        }
    };

    stage_kv(0, 0);
    __syncthreads();

    bf16x8 QB[2][2];
#pragma unroll
    for (int ni = 0; ni < 2; ++ni)
#pragma unroll
        for (int ds = 0; ds < 2; ++ds) {
            int q = wv * 32 + ni * 16 + c;
            QB[ni][ds] = *(const bf16x8*)(Qs + q * 128 + ((ds * 64 + g * 16) ^ ((q & 7) << 4)));
        }

    float m_run[2] = {-1e30f, -1e30f};
    float l_run[2] = {0.f, 0.f};
    f32x4 acc[2][4] = {};
    unsigned char* Pw = Pb + wv * 4096;
    float* corw = corr + wv * 32;

    for (int kt = 0; kt < 2; ++kt) {
        int bb = kt & 1;
        if (kt < 1) stage_kv(kt + 1, bb ^ 1);

        unsigned char* kb = Kb + bb * 8192;
        unsigned char* vb = Vb + bb * 8192;
        bf16x8 KA[4][2];
#pragma unroll
        for (int mi = 0; mi < 4; ++mi)
#pragma unroll
            for (int ds = 0; ds < 2; ++ds) {
                int key = mi * 16 + c;
                KA[mi][ds] = *(const bf16x8*)(kb + key * 128 + ((ds * 64 + g * 16) ^ ((key & 7) << 4)));
            }
        f32x4 sc[4][2] = {};
#pragma unroll
        for (int mi = 0; mi < 4; ++mi)
#pragma unroll
            for (int ni = 0; ni < 2; ++ni) {
                sc[mi][ni] = __builtin_amdgcn_mfma_f32_16x16x32_bf16(KA[mi][0], QB[ni][0], sc[mi][ni], 0, 0, 0);
                sc[mi][ni] = __builtin_amdgcn_mfma_f32_16x16x32_bf16(KA[mi][1], QB[ni][1], sc[mi][ni], 0, 0, 0);
            }
#pragma unroll
        for (int ni = 0; ni < 2; ++ni) {
            float mt = sc[0][ni][0];
#pragma unroll
            for (int mi = 0; mi < 4; ++mi)
#pragma unroll
                for (int r = 0; r < 4; ++r) mt = fmaxf(mt, sc[mi][ni][r]);
            mt = fmaxf(mt, __shfl_xor(mt, 16));
            mt = fmaxf(mt, __shfl_xor(mt, 32));
            float mnew = fmaxf(m_run[ni], mt);
            float co = __expf(m_run[ni] - mnew);
            m_run[ni] = mnew;
            float ps = 0.f;
            int q = ni * 16 + c;
#pragma unroll
            for (int mi = 0; mi < 4; ++mi) {
                float p0 = __expf(sc[mi][ni][0] - mnew);
                float p1 = __expf(sc[mi][ni][1] - mnew);
                float p2 = __expf(sc[mi][ni][2] - mnew);
                float p3 = __expf(sc[mi][ni][3] - mnew);
                ps += (p0 + p1) + (p2 + p3);
                *(unsigned long long*)(Pw + q * 128 + ((2 * (mi * 16 + g * 4)) ^ ((q & 7) << 4))) =
                    pack4bf(p0, p1, p2, p3);
            }
            ps += __shfl_xor(ps, 16);
            ps += __shfl_xor(ps, 32);
            l_run[ni] = l_run[ni] * co + ps;
            if (g == 0) corw[q] = co;
        }
        LDS_FENCE();
#pragma unroll
        for (int mf = 0; mf < 2; ++mf) {
            float cr0 = corw[mf * 16 + g * 4 + 0];
            float cr1 = corw[mf * 16 + g * 4 + 1];
            float cr2 = corw[mf * 16 + g * 4 + 2];
            float cr3 = corw[mf * 16 + g * 4 + 3];
#pragma unroll
            for (int nf = 0; nf < 4; ++nf) {
                acc[mf][nf][0] *= cr0; acc[mf][nf][1] *= cr1;
                acc[mf][nf][2] *= cr2; acc[mf][nf][3] *= cr3;
            }
        }
        bf16x8 PA[2][2], VBf[4][2];
#pragma unroll
        for (int mf = 0; mf < 2; ++mf)
#pragma unroll
            for (int ks = 0; ks < 2; ++ks) {
                int q = mf * 16 + c;
                PA[mf][ks] = *(const bf16x8*)(Pw + q * 128 + ((ks * 64 + g * 16) ^ ((q & 7) << 4)));
            }
#pragma unroll
        for (int nf = 0; nf < 4; ++nf)
#pragma unroll
            for (int ks = 0; ks < 2; ++ks) {
                int d = nf * 16 + c;
                VBf[nf][ks] = *(const bf16x8*)(vb + d * 128 + ((ks * 64 + g * 16) ^ (((d >> 2) & 7) << 4)));
            }
#pragma unroll
        for (int mf = 0; mf < 2; ++mf)
#pragma unroll
            for (int nf = 0; nf < 4; ++nf) {
                acc[mf][nf] = __builtin_amdgcn_mfma_f32_16x16x32_bf16(PA[mf][0], VBf[nf][0], acc[mf][nf], 0, 0, 0);
                acc[mf][nf] = __builtin_amdgcn_mfma_f32_16x16x32_bf16(PA[mf][1], VBf[nf][1], acc[mf][nf], 0, 0, 0);
            }
        __syncthreads();
    }

    if (g == 0) { corw[c] = 1.f / l_run[0]; corw[16 + c] = 1.f / l_run[1]; }
    LDS_FENCE();
#pragma unroll
    for (int mf = 0; mf < 2; ++mf) {
        float iv[4];
#pragma unroll
        for (int r = 0; r < 4; ++r) iv[r] = corw[mf * 16 + g * 4 + r];
#pragma unroll
        for (int r = 0; r < 4; ++r) {
            size_t row = (size_t)b * S + (size_t)qt * 128 + wv * 32 + mf * 16 + g * 4 + r;
#pragma unroll
            for (int nf = 0; nf < 4; ++nf) {
                int col = h * HD + nf * 16 + c;
                glob_bf[row * D + col] = f2bf(acc[mf][nf][r] * iv[r]);
            }
        }
    }
}

// ---------------------------------------------------------------- kernels 5/6: bf16 MFMA GEMMs
// 1D grid of 1024 blocks with bijective XCD swizzle (T1): each XCD owns 16 consecutive
// M-panels x all 8 N-tiles, so each A-panel lives in exactly one XCD L2.
// MODE 0: A=[local_bf|glob_bf] (K=2048) x wTg -> sigmoid blend (from bf16 A0/A1) -> mixed_bf
// MODE 1: A=mixed_bf (K=1024) x wTo + out_b -> d_out (f32)
template <int MODE>
__launch_bounds__(256)
__global__ void k_mgemm(const unsigned short* __restrict__ A0,
                        const unsigned short* __restrict__ A1,
                        const unsigned short* __restrict__ BT,
                        const float* __restrict__ bias,
                        void* __restrict__ Cout) {
    constexpr int K = (MODE == 0) ? 2048 : 1024;
    __shared__ __align__(16) unsigned short As[128 * 32];
    __shared__ __align__(16) unsigned short Bs[128 * 32];
    const int t = threadIdx.x;
    const int wv = t >> 6, ln = t & 63;
    const int lrow = ln & 15, lk = ln >> 4;
    const int wr = wv >> 1, wc = wv & 1;

    int lin = blockIdx.x;
    int swz = (lin & 7) * 128 + (lin >> 3);   // bijective: 1024 % 8 == 0
    const int bn = (swz & 7) * 128;
    const int bm = (swz >> 3) * 128;

    const int arow = ln >> 2;
    const int acol8 = (ln & 3) * 8;

    f32x4 acc[4][4] = {};

    for (int k0 = 0; k0 < K; k0 += 32) {
        const unsigned short* Ab;
        int kloc;
        if constexpr (MODE == 0) { Ab = (k0 < 1024) ? A0 : A1; kloc = k0 & 1023; }
        else                     { Ab = A0; kloc = k0; }
        gload16(Ab + (size_t)(bm + wv * 32 + arow) * 1024 + kloc + acol8,
                As + wv * 32 * 32);
        gload16(Ab + (size_t)(bm + wv * 32 + 16 + arow) * 1024 + kloc + acol8,
                As + wv * 32 * 32 + 16 * 32);
        gload16(BT + (size_t)(bn + wv * 32 + arow) * K + k0 + acol8,
                Bs + wv * 32 * 32);
        gload16(BT + (size_t)(bn + wv * 32 + 16 + arow) * K + k0 + acol8,
                Bs + wv * 32 * 32 + 16 * 32);
        __syncthreads();
        bf16x8 af[4], bfr[4];
#pragma unroll
        for (int m = 0; m < 4; ++m)
            af[m] = *(const bf16x8*)(As + (wr * 64 + m * 16 + lrow) * 32 + lk * 8);
#pragma unroll
        for (int n = 0; n < 4; ++n)
            bfr[n] = *(const bf16x8*)(Bs + (wc * 64 + n * 16 + lrow) * 32 + lk * 8);
#pragma unroll
        for (int m = 0; m < 4; ++m)
#pragma unroll
            for (int n = 0; n < 4; ++n)
                acc[m][n] = __builtin_amdgcn_mfma_f32_16x16x32_bf16(af[m], bfr[n], acc[m][n], 0, 0, 0);
        __syncthreads();
    }

#pragma unroll
    for (int m = 0; m < 4; ++m) {
#pragma unroll
        for (int n = 0; n < 4; ++n) {
            int col = bn + wc * 64 + n * 16 + lrow;
            float bv = bias[col];
#pragma unroll
            for (int r = 0; r < 4; ++r) {
                int row = bm + wr * 64 + m * 16 + lk * 4 + r;
                size_t off = (size_t)row * 1024 + col;
                float v = acc[m][n][r] + bv;
                if constexpr (MODE == 0) {
                    float mixv = 1.f / (1.f + __expf(-v));
                    float o = mixv * bf2f(A0[off]) + (1.f - mixv) * bf2f(A1[off]);
                    ((unsigned short*)Cout)[off] = f2bf(o);
                } else {
                    ((float*)Cout)[off] = v;
                }
            }
        }
    }
}

// ---------------------------------------------------------------- launch
extern "C" void kernel_launch(void* const* d_in, const int* in_sizes, int n_in,
                              void* d_out, int out_size, void* d_ws, size_t ws_size,
                              hipStream_t stream) {
    (void)in_sizes; (void)n_in; (void)out_size; (void)ws_size;
    const float* x     = (const float*)d_in[0];
    const float* pos   = (const float*)d_in[1];
    const float* gmem  = (const float*)d_in[2];
    const float* convw = (const float*)d_in[3];
    const float* convb = (const float*)d_in[4];
    const float* gatew = (const float*)d_in[5];
    const float* gateb = (const float*)d_in[6];
    const float* outw  = (const float*)d_in[7];
    const float* outb  = (const float*)d_in[8];

    float* ws = (float*)d_ws;
    float* xe    = ws;                                    // 16,777,216 f
    float* hole  = xe + 16777216;                         // (was globf; unused)
    float* gt    = hole + 16777216;                       //    524,288 f
    float* part  = gt + 524288;                           //  1,048,576 f
    unsigned short* local_bf = (unsigned short*)(part + 1048576);  // 16M u16
    unsigned short* glob_bf  = local_bf + 16777216;                // 16M u16
    unsigned short* wTg      = glob_bf + 16777216;                 //  2M u16
    unsigned short* wTo      = wTg + 2097152;                      //  1M u16
    unsigned short* mixed_bf = (unsigned short*)xe;       // alias: xe dead after globattn

    k_posadd  <<<16384, 256, 0, stream>>>(x, pos, xe);
    k_wtrans<2048><<<dim3(64, 32), 256, 0, stream>>>(gatew, wTg);
    k_wtrans<1024><<<dim3(32, 32), 256, 0, stream>>>(outw, wTo);
    k_winattn <<<B * NW * H * 4, 256, 0, stream>>>(xe, local_bf);
    k_conv_part<<<256, 256, 0, stream>>>(xe, convw, part);
    k_gt      <<<512, 256, 0, stream>>>(part, convb, gmem, gt);
    k_globattn<<<B * H * (S / 128), 256, 0, stream>>>(xe, gt, glob_bf);
    k_mgemm<0><<<1024, 256, 0, stream>>>(local_bf, glob_bf, wTg, gateb, mixed_bf);
    k_mgemm<1><<<1024, 256, 0, stream>>>(mixed_bf, nullptr, wTo, outb, d_out);
}

// Round 9
// 504.694 us; speedup vs baseline: 4.2347x; 1.0210x over previous
//
#include <hip/hip_runtime.h>
#include <math.h>

#define B 4
#define S 4096
#define D 1024
#define H 16
#define HD 64
#define WIN 512
#define NW 8
#define G 64
#define G2 128
#define SCALE 0.125f

typedef __attribute__((ext_vector_type(8))) short bf16x8;
typedef __attribute__((ext_vector_type(4))) float f32x4;

__device__ inline unsigned short f2bf(float f) {
    unsigned u = __builtin_bit_cast(unsigned, f);
    return (unsigned short)((u + 0x7FFFu + ((u >> 16) & 1u)) >> 16);
}

__device__ inline float bf2f(unsigned short u) {
    return __builtin_bit_cast(float, (unsigned)u << 16);
}

__device__ inline unsigned long long pack4bf(float a, float b, float c, float d) {
    return (unsigned long long)f2bf(a) | ((unsigned long long)f2bf(b) << 16) |
           ((unsigned long long)f2bf(c) << 32) | ((unsigned long long)f2bf(d) << 48);
}

__device__ inline void gload16(const void* g, void* l) {
    __builtin_amdgcn_global_load_lds(
        (const __attribute__((address_space(1))) unsigned*)g,
        (__attribute__((address_space(3))) unsigned*)l, 16, 0, 0);
}

// compiler-only ordering fence for LDS write->read hand-offs (HW DS is in-order per wave)
#define LDS_FENCE() asm volatile("" ::: "memory")

// ---------------------------------------------------------------- weight transpose + bf16
template <int KD>
__global__ void k_wtrans(const float* __restrict__ w, unsigned short* __restrict__ wT) {
    __shared__ float tile[32][33];
    int k0 = blockIdx.x * 32, n0 = blockIdx.y * 32;
    int tx = threadIdx.x & 31, ty = threadIdx.x >> 5;
#pragma unroll
    for (int i = 0; i < 4; ++i)
        tile[ty + 8 * i][tx] = w[(size_t)(k0 + ty + 8 * i) * 1024 + n0 + tx];
    __syncthreads();
#pragma unroll
    for (int i = 0; i < 4; ++i)
        wT[(size_t)(n0 + ty + 8 * i) * KD + k0 + tx] = f2bf(tile[tx][ty + 8 * i]);
}

// ---------------------------------------------------------------- kernel 2: MFMA window attention
// pos-add fused into Q/KV staging (posadd kernel eliminated).
// bid remap: blocks sharing one (b,wi) window land on one XCD (T1 KV L2 locality).
__launch_bounds__(256)
__global__ void k_winattn(const float* __restrict__ x, const float* __restrict__ pos,
                          unsigned short* __restrict__ local_bf) {
    int blk = blockIdx.x;
    int xcd = blk & 7, rest = blk >> 3;
    int g2 = xcd * 4 + (rest >> 6);          // 0..31 window group
    int inner = rest & 63;                   // 0..63
    int qt = inner & 3, h = inner >> 2;
    int wi = g2 & 7, b = g2 >> 3;

    __shared__ __align__(16) unsigned char lds[66048];
    unsigned char* Qs = lds;                 // [128][64] bf16, swz by q       16 KB
    unsigned char* Kb = lds + 16384;         // 2x [64][64] bf16, swz by key   16 KB
    unsigned char* Vb = lds + 32768;         // 2x [64 d][64 key] bf16, swz d>>2 16 KB
    unsigned char* Pb = lds + 49152;         // 4x [32][64] bf16, swz by q     16 KB
    float* corr = (float*)(lds + 65536);     // 4 x 32 floats

    const int t = threadIdx.x;
    const int wv = t >> 6, l = t & 63;
    const int g = l >> 4, c = l & 15;

    const float* xb = x + ((size_t)b * S + (size_t)wi * WIN) * D + h * HD;
    const float* pb = pos + (size_t)wi * WIN * D + h * HD;

#pragma unroll
    for (int p = 0; p < 8; ++p) {
        int i = t + 256 * p;
        int q = i >> 4, c4 = i & 15;
        size_t off = (size_t)(qt * 128 + q) * D + c4 * 4;
        float4 v = *(const float4*)(xb + off);
        float4 pv = *(const float4*)(pb + off);
        v.x += pv.x; v.y += pv.y; v.z += pv.z; v.w += pv.w;
        *(unsigned long long*)(Qs + q * 128 + ((c4 * 8) ^ ((q & 7) << 4))) =
            pack4bf(v.x * SCALE, v.y * SCALE, v.z * SCALE, v.w * SCALE);
    }

    auto stage_kv = [&](int kt, int bb) {
        unsigned char* kb = Kb + bb * 8192;
        unsigned char* vb = Vb + bb * 8192;
#pragma unroll
        for (int p = 0; p < 4; ++p) {
            int i = t + 256 * p;
            int key = i >> 4, c4 = i & 15;
            size_t off = (size_t)(kt * 64 + key) * D + c4 * 4;
            float4 v = *(const float4*)(xb + off);
            float4 pv = *(const float4*)(pb + off);
            v.x += pv.x; v.y += pv.y; v.z += pv.z; v.w += pv.w;
            *(unsigned long long*)(kb + key * 128 + ((c4 * 8) ^ ((key & 7) << 4))) =
                pack4bf(v.x, v.y, v.z, v.w);
            int swz = (c4 & 7) << 4;
            int d0 = c4 * 4;
            *(unsigned short*)(vb + (d0 + 0) * 128 + ((key * 2) ^ swz)) = f2bf(v.x);
            *(unsigned short*)(vb + (d0 + 1) * 128 + ((key * 2) ^ swz)) = f2bf(v.y);
            *(unsigned short*)(vb + (d0 + 2) * 128 + ((key * 2) ^ swz)) = f2bf(v.z);
            *(unsigned short*)(vb + (d0 + 3) * 128 + ((key * 2) ^ swz)) = f2bf(v.w);
        }
    };

    stage_kv(0, 0);
    __syncthreads();

    bf16x8 QB[2][2];
#pragma unroll
    for (int ni = 0; ni < 2; ++ni)
#pragma unroll
        for (int ds = 0; ds < 2; ++ds) {
            int q = wv * 32 + ni * 16 + c;
            QB[ni][ds] = *(const bf16x8*)(Qs + q * 128 + ((ds * 64 + g * 16) ^ ((q & 7) << 4)));
        }

    float m_run[2] = {-1e30f, -1e30f};
    float l_run[2] = {0.f, 0.f};
    f32x4 acc[2][4] = {};
    unsigned char* Pw = Pb + wv * 4096;
    float* corw = corr + wv * 32;

    for (int kt = 0; kt < 8; ++kt) {
        int bb = kt & 1;
        if (kt < 7) stage_kv(kt + 1, bb ^ 1);

        unsigned char* kb = Kb + bb * 8192;
        unsigned char* vb = Vb + bb * 8192;
        bf16x8 KA[4][2];
#pragma unroll
        for (int mi = 0; mi < 4; ++mi)
#pragma unroll
            for (int ds = 0; ds < 2; ++ds) {
                int key = mi * 16 + c;
                KA[mi][ds] = *(const bf16x8*)(kb + key * 128 + ((ds * 64 + g * 16) ^ ((key & 7) << 4)));
            }
        f32x4 sc[4][2] = {};
#pragma unroll
        for (int mi = 0; mi < 4; ++mi)
#pragma unroll
            for (int ni = 0; ni < 2; ++ni) {
                sc[mi][ni] = __builtin_amdgcn_mfma_f32_16x16x32_bf16(KA[mi][0], QB[ni][0], sc[mi][ni], 0, 0, 0);
                sc[mi][ni] = __builtin_amdgcn_mfma_f32_16x16x32_bf16(KA[mi][1], QB[ni][1], sc[mi][ni], 0, 0, 0);
            }
#pragma unroll
        for (int ni = 0; ni < 2; ++ni) {
            float mt = sc[0][ni][0];
#pragma unroll
            for (int mi = 0; mi < 4; ++mi)
#pragma unroll
                for (int r = 0; r < 4; ++r) mt = fmaxf(mt, sc[mi][ni][r]);
            mt = fmaxf(mt, __shfl_xor(mt, 16));
            mt = fmaxf(mt, __shfl_xor(mt, 32));
            float mnew = fmaxf(m_run[ni], mt);
            float co = __expf(m_run[ni] - mnew);
            m_run[ni] = mnew;
            float ps = 0.f;
            int q = ni * 16 + c;
#pragma unroll
            for (int mi = 0; mi < 4; ++mi) {
                float p0 = __expf(sc[mi][ni][0] - mnew);
                float p1 = __expf(sc[mi][ni][1] - mnew);
                float p2 = __expf(sc[mi][ni][2] - mnew);
                float p3 = __expf(sc[mi][ni][3] - mnew);
                ps += (p0 + p1) + (p2 + p3);
                *(unsigned long long*)(Pw + q * 128 + ((2 * (mi * 16 + g * 4)) ^ ((q & 7) << 4))) =
                    pack4bf(p0, p1, p2, p3);
            }
            ps += __shfl_xor(ps, 16);
            ps += __shfl_xor(ps, 32);
            l_run[ni] = l_run[ni] * co + ps;
            if (g == 0) corw[q] = co;
        }
        LDS_FENCE();
#pragma unroll
        for (int mf = 0; mf < 2; ++mf) {
            float cr0 = corw[mf * 16 + g * 4 + 0];
            float cr1 = corw[mf * 16 + g * 4 + 1];
            float cr2 = corw[mf * 16 + g * 4 + 2];
            float cr3 = corw[mf * 16 + g * 4 + 3];
#pragma unroll
            for (int nf = 0; nf < 4; ++nf) {
                acc[mf][nf][0] *= cr0; acc[mf][nf][1] *= cr1;
                acc[mf][nf][2] *= cr2; acc[mf][nf][3] *= cr3;
            }
        }
        bf16x8 PA[2][2], VBf[4][2];
#pragma unroll
        for (int mf = 0; mf < 2; ++mf)
#pragma unroll
            for (int ks = 0; ks < 2; ++ks) {
                int q = mf * 16 + c;
                PA[mf][ks] = *(const bf16x8*)(Pw + q * 128 + ((ks * 64 + g * 16) ^ ((q & 7) << 4)));
            }
#pragma unroll
        for (int nf = 0; nf < 4; ++nf)
#pragma unroll
            for (int ks = 0; ks < 2; ++ks) {
                int d = nf * 16 + c;
                VBf[nf][ks] = *(const bf16x8*)(vb + d * 128 + ((ks * 64 + g * 16) ^ (((d >> 2) & 7) << 4)));
            }
#pragma unroll
        for (int mf = 0; mf < 2; ++mf)
#pragma unroll
            for (int nf = 0; nf < 4; ++nf) {
                acc[mf][nf] = __builtin_amdgcn_mfma_f32_16x16x32_bf16(PA[mf][0], VBf[nf][0], acc[mf][nf], 0, 0, 0);
                acc[mf][nf] = __builtin_amdgcn_mfma_f32_16x16x32_bf16(PA[mf][1], VBf[nf][1], acc[mf][nf], 0, 0, 0);
            }
        __syncthreads();
    }

    if (g == 0) { corw[c] = 1.f / l_run[0]; corw[16 + c] = 1.f / l_run[1]; }
    LDS_FENCE();
#pragma unroll
    for (int mf = 0; mf < 2; ++mf) {
        float iv[4];
#pragma unroll
        for (int r = 0; r < 4; ++r) iv[r] = corw[mf * 16 + g * 4 + r];
#pragma unroll
        for (int r = 0; r < 4; ++r) {
            size_t row = (size_t)b * S + (size_t)wi * WIN + qt * 128 + wv * 32 + mf * 16 + g * 4 + r;
#pragma unroll
            for (int nf = 0; nf < 4; ++nf) {
                int col = h * HD + nf * 16 + c;
                local_bf[row * D + col] = f2bf(acc[mf][nf][r] * iv[r]);
            }
        }
    }
}

// ---------------------------------------------------------------- kernel 3a: conv as split-K GEMM
// pos-add fused into the A-tile load.
__launch_bounds__(256)
__global__ void k_conv_part(const float* __restrict__ x, const float* __restrict__ pos,
                            const float* __restrict__ convw, float* __restrict__ part) {
    int bid = blockIdx.x;
    int nt = bid & 15, mt = (bid >> 4) & 3, kc = bid >> 6;
    __shared__ float As[32][68];
    __shared__ float Bs[32][68];
    int t = threadIdx.x, tx = t & 15, ty = t >> 4;
    float acc[4][4] = {};
    for (int k0 = 0; k0 < 1024; k0 += 32) {
#pragma unroll
        for (int p = 0; p < 2; ++p) {
            int fidx = t + 256 * p;
            int am = fidx >> 3, ak4 = fidx & 7;
            int bg = mt * 64 + am, b = bg >> 6, g = bg & 63;
            float4 v = *(const float4*)(x + ((size_t)b * S + 4 * g + kc) * D + k0 + ak4 * 4);
            float4 pv = *(const float4*)(pos + (size_t)(4 * g + kc) * D + k0 + ak4 * 4);
            v.x += pv.x; v.y += pv.y; v.z += pv.z; v.w += pv.w;
            As[ak4*4+0][am] = v.x; As[ak4*4+1][am] = v.y;
            As[ak4*4+2][am] = v.z; As[ak4*4+3][am] = v.w;
        }
#pragma unroll
        for (int p = 0; p < 8; ++p) {
            int bk = t & 31, bn = (t >> 5) + 8 * p;
            Bs[bk][bn] = convw[(size_t)(nt * 64 + bn) * 4096 + (size_t)(k0 + bk) * 4 + kc];
        }
        __syncthreads();
#pragma unroll
        for (int kk = 0; kk < 32; ++kk) {
            float a[4], bb[4];
            *(float4*)a  = *(const float4*)(&As[kk][ty * 4]);
            *(float4*)bb = *(const float4*)(&Bs[kk][tx * 4]);
#pragma unroll
            for (int i = 0; i < 4; ++i)
#pragma unroll
                for (int j = 0; j < 4; ++j)
                    acc[i][j] = fmaf(a[i], bb[j], acc[i][j]);
        }
        __syncthreads();
    }
#pragma unroll
    for (int i = 0; i < 4; ++i) {
        size_t off = ((size_t)kc * 256 + mt * 64 + ty * 4 + i) * 1024 + nt * 64 + tx * 4;
        *(float4*)(part + off) = make_float4(acc[i][0], acc[i][1], acc[i][2], acc[i][3]);
    }
}

// ---------------------------------------------------------------- kernel 3b: assemble gt
__global__ void k_gt(const float* __restrict__ part, const float* __restrict__ convb,
                     const float* __restrict__ gmem, float* __restrict__ gt) {
    int f = blockIdx.x * blockDim.x + threadIdx.x;
    int n4  = f & 255;
    int tok = (f >> 8) & 127;
    int b   = f >> 15;
    float4 v;
    if (tok < 64) {
        v = ((const float4*)convb)[n4];
#pragma unroll
        for (int kc = 0; kc < 4; ++kc) {
            float4 p = ((const float4*)part)[((size_t)kc * 256 + b * 64 + tok) * 256 + n4];
            v.x += p.x; v.y += p.y; v.z += p.z; v.w += p.w;
        }
    } else {
        v = ((const float4*)gmem)[(size_t)(tok - 64) * 256 + n4];
    }
    ((float4*)gt)[f] = v;
}

// ---------------------------------------------------------------- kernel 4: MFMA global attention
// pos-add fused into Q staging.
__launch_bounds__(256)
__global__ void k_globattn(const float* __restrict__ x, const float* __restrict__ pos,
                           const float* __restrict__ gt, unsigned short* __restrict__ glob_bf) {
    int blk = blockIdx.x;
    int qt = blk & 31, h = (blk >> 5) & 15, b = blk >> 9;

    __shared__ __align__(16) unsigned char lds[66048];
    unsigned char* Qs = lds;
    unsigned char* Kb = lds + 16384;
    unsigned char* Vb = lds + 32768;
    unsigned char* Pb = lds + 49152;
    float* corr = (float*)(lds + 65536);

    const int t = threadIdx.x;
    const int wv = t >> 6, l = t & 63;
    const int g = l >> 4, c = l & 15;

    const float* qbx = x + ((size_t)b * S + (size_t)qt * 128) * D + h * HD;
    const float* qbp = pos + (size_t)qt * 128 * D + h * HD;
    const float* kvbase = gt + (size_t)b * G2 * D + h * HD;

#pragma unroll
    for (int p = 0; p < 8; ++p) {
        int i = t + 256 * p;
        int q = i >> 4, c4 = i & 15;
        size_t off = (size_t)q * D + c4 * 4;
        float4 v = *(const float4*)(qbx + off);
        float4 pv = *(const float4*)(qbp + off);
        v.x += pv.x; v.y += pv.y; v.z += pv.z; v.w += pv.w;
        *(unsigned long long*)(Qs + q * 128 + ((c4 * 8) ^ ((q & 7) << 4))) =
            pack4bf(v.x * SCALE, v.y * SCALE, v.z * SCALE, v.w * SCALE);
    }

    auto stage_kv = [&](int kt, int bb) {
        unsigned char* kb = Kb + bb * 8192;
        unsigned char* vb = Vb + bb * 8192;
#pragma unroll
        for (int p = 0; p < 4; ++p) {
            int i = t + 256 * p;
            int key = i >> 4, c4 = i & 15;
            float4 v = *(const float4*)(kvbase + (size_t)(kt * 64 + key) * D + c4 * 4);
            *(unsigned long long*)(kb + key * 128 + ((c4 * 8) ^ ((key & 7) << 4))) =
                pack4bf(v.x, v.y, v.z, v.w);
            int swz = (c4 & 7) << 4;
            int d0 = c4 * 4;
            *(unsigned short*)(vb + (d0 + 0) * 128 + ((key * 2) ^ swz)) = f2bf(v.x);
            *(unsigned short*)(vb + (d0 + 1) * 128 + ((key * 2) ^ swz)) = f2bf(v.y);
            *(unsigned short*)(vb + (d0 + 2) * 128 + ((key * 2) ^ swz)) = f2bf(v.z);
            *(unsigned short*)(vb + (d0 + 3) * 128 + ((key * 2) ^ swz)) = f2bf(v.w);
        }
    };

    stage_kv(0, 0);
    __syncthreads();

    bf16x8 QB[2][2];
#pragma unroll
    for (int ni = 0; ni < 2; ++ni)
#pragma unroll
        for (int ds = 0; ds < 2; ++ds) {
            int q = wv * 32 + ni * 16 + c;
            QB[ni][ds] = *(const bf16x8*)(Qs + q * 128 + ((ds * 64 + g * 16) ^ ((q & 7) << 4)));
        }

    float m_run[2] = {-1e30f, -1e30f};
    float l_run[2] = {0.f, 0.f};
    f32x4 acc[2][4] = {};
    unsigned char* Pw = Pb + wv * 4096;
    float* corw = corr + wv * 32;

    for (int kt = 0; kt < 2; ++kt) {
        int bb = kt & 1;
        if (kt < 1) stage_kv(kt + 1, bb ^ 1);

        unsigned char* kb = Kb + bb * 8192;
        unsigned char* vb = Vb + bb * 8192;
        bf16x8 KA[4][2];
#pragma unroll
        for (int mi = 0; mi < 4; ++mi)
#pragma unroll
            for (int ds = 0; ds < 2; ++ds) {
                int key = mi * 16 + c;
                KA[mi][ds] = *(const bf16x8*)(kb + key * 128 + ((ds * 64 + g * 16) ^ ((key & 7) << 4)));
            }
        f32x4 sc[4][2] = {};
#pragma unroll
        for (int mi = 0; mi < 4; ++mi)
#pragma unroll
            for (int ni = 0; ni < 2; ++ni) {
                sc[mi][ni] = __builtin_amdgcn_mfma_f32_16x16x32_bf16(KA[mi][0], QB[ni][0], sc[mi][ni], 0, 0, 0);
                sc[mi][ni] = __builtin_amdgcn_mfma_f32_16x16x32_bf16(KA[mi][1], QB[ni][1], sc[mi][ni], 0, 0, 0);
            }
#pragma unroll
        for (int ni = 0; ni < 2; ++ni) {
            float mt = sc[0][ni][0];
#pragma unroll
            for (int mi = 0; mi < 4; ++mi)
#pragma unroll
                for (int r = 0; r < 4; ++r) mt = fmaxf(mt, sc[mi][ni][r]);
            mt = fmaxf(mt, __shfl_xor(mt, 16));
            mt = fmaxf(mt, __shfl_xor(mt, 32));
            float mnew = fmaxf(m_run[ni], mt);
            float co = __expf(m_run[ni] - mnew);
            m_run[ni] = mnew;
            float ps = 0.f;
            int q = ni * 16 + c;
#pragma unroll
            for (int mi = 0; mi < 4; ++mi) {
                float p0 = __expf(sc[mi][ni][0] - mnew);
                float p1 = __expf(sc[mi][ni][1] - mnew);
                float p2 = __expf(sc[mi][ni][2] - mnew);
                float p3 = __expf(sc[mi][ni][3] - mnew);
                ps += (p0 + p1) + (p2 + p3);
                *(unsigned long long*)(Pw + q * 128 + ((2 * (mi * 16 + g * 4)) ^ ((q & 7) << 4))) =
                    pack4bf(p0, p1, p2, p3);
            }
            ps += __shfl_xor(ps, 16);
            ps += __shfl_xor(ps, 32);
            l_run[ni] = l_run[ni] * co + ps;
            if (g == 0) corw[q] = co;
        }
        LDS_FENCE();
#pragma unroll
        for (int mf = 0; mf < 2; ++mf) {
            float cr0 = corw[mf * 16 + g * 4 + 0];
            float cr1 = corw[mf * 16 + g * 4 + 1];
            float cr2 = corw[mf * 16 + g * 4 + 2];
            float cr3 = corw[mf * 16 + g * 4 + 3];
#pragma unroll
            for (int nf = 0; nf < 4; ++nf) {
                acc[mf][nf][0] *= cr0; acc[mf][nf][1] *= cr1;
                acc[mf][nf][2] *= cr2; acc[mf][nf][3] *= cr3;
            }
        }
        bf16x8 PA[2][2], VBf[4][2];
#pragma unroll
        for (int mf = 0; mf < 2; ++mf)
#pragma unroll
            for (int ks = 0; ks < 2; ++ks) {
                int q = mf * 16 + c;
                PA[mf][ks] = *(const bf16x8*)(Pw + q * 128 + ((ks * 64 + g * 16) ^ ((q & 7) << 4)));
            }
#pragma unroll
        for (int nf = 0; nf < 4; ++nf)
#pragma unroll
            for (int ks = 0; ks < 2; ++ks) {
                int d = nf * 16 + c;
                VBf[nf][ks] = *(const bf16x8*)(vb + d * 128 + ((ks * 64 + g * 16) ^ (((d >> 2) & 7) << 4)));
            }
#pragma unroll
        for (int mf = 0; mf < 2; ++mf)
#pragma unroll
            for (int nf = 0; nf < 4; ++nf) {
                acc[mf][nf] = __builtin_amdgcn_mfma_f32_16x16x32_bf16(PA[mf][0], VBf[nf][0], acc[mf][nf], 0, 0, 0);
                acc[mf][nf] = __builtin_amdgcn_mfma_f32_16x16x32_bf16(PA[mf][1], VBf[nf][1], acc[mf][nf], 0, 0, 0);
            }
        __syncthreads();
    }

    if (g == 0) { corw[c] = 1.f / l_run[0]; corw[16 + c] = 1.f / l_run[1]; }
    LDS_FENCE();
#pragma unroll
    for (int mf = 0; mf < 2; ++mf) {
        float iv[4];
#pragma unroll
        for (int r = 0; r < 4; ++r) iv[r] = corw[mf * 16 + g * 4 + r];
#pragma unroll
        for (int r = 0; r < 4; ++r) {
            size_t row = (size_t)b * S + (size_t)qt * 128 + wv * 32 + mf * 16 + g * 4 + r;
#pragma unroll
            for (int nf = 0; nf < 4; ++nf) {
                int col = h * HD + nf * 16 + c;
                glob_bf[row * D + col] = f2bf(acc[mf][nf][r] * iv[r]);
            }
        }
    }
}

// ---------------------------------------------------------------- kernels 5/6: bf16 MFMA GEMMs
// BK=64 (32 MFMA per barrier-drain, halves barrier count) + XOR-swizzled LDS:
// gload_lds writes linearly; source chunk pre-swizzled per-lane (m173); ds_read
// applies byte ^= ((row&7)<<4)  ->  frag reads are 2-way (free) instead of 8-way.
template <int MODE>
__launch_bounds__(256)
__global__ void k_mgemm(const unsigned short* __restrict__ A0,
                        const unsigned short* __restrict__ A1,
                        const unsigned short* __restrict__ BT,
                        const float* __restrict__ bias,
                        void* __restrict__ Cout) {
    constexpr int K = (MODE == 0) ? 2048 : 1024;
    __shared__ __align__(16) unsigned short As[128 * 64];
    __shared__ __align__(16) unsigned short Bs[128 * 64];
    const int t = threadIdx.x;
    const int wv = t >> 6, ln = t & 63;
    const int lrow = ln & 15, lk = ln >> 4;
    const int wr = wv >> 1, wc = wv & 1;

    int lin = blockIdx.x;
    int swz = (lin & 7) * 128 + (lin >> 3);   // bijective XCD swizzle: 1024 % 8 == 0
    const int bn = (swz & 7) * 128;
    const int bm = (swz >> 3) * 128;

    const int srow = ln >> 3;                           // row within 8-row group
    const int schunk = ((ln & 7) ^ (ln >> 3)) * 8;      // pre-swizzled source col (bf16)

    f32x4 acc[4][4] = {};

    for (int k0 = 0; k0 < K; k0 += 64) {
        const unsigned short* Ab;
        int kloc;
        if constexpr (MODE == 0) { Ab = (k0 < 1024) ? A0 : A1; kloc = k0 & 1023; }
        else                     { Ab = A0; kloc = k0; }
        // each wave stages 32 rows of A and 32 rows of B^T (4 x gload16 of 8 rows each)
#pragma unroll
        for (int j = 0; j < 4; ++j) {
            int r0 = wv * 32 + j * 8;
            gload16(Ab + (size_t)(bm + r0 + srow) * 1024 + kloc + schunk, As + r0 * 64);
            gload16(BT + (size_t)(bn + r0 + srow) * K + k0 + schunk,      Bs + r0 * 64);
        }
        __syncthreads();
        bf16x8 af[4][2], bfr[4][2];
#pragma unroll
        for (int m = 0; m < 4; ++m) {
            int row = wr * 64 + m * 16 + lrow;
#pragma unroll
            for (int ks = 0; ks < 2; ++ks)
                af[m][ks] = *(const bf16x8*)((const unsigned char*)As + row * 128 +
                                ((ks * 64 + lk * 16) ^ ((row & 7) << 4)));
        }
#pragma unroll
        for (int n = 0; n < 4; ++n) {
            int row = wc * 64 + n * 16 + lrow;
#pragma unroll
            for (int ks = 0; ks < 2; ++ks)
                bfr[n][ks] = *(const bf16x8*)((const unsigned char*)Bs + row * 128 +
                                ((ks * 64 + lk * 16) ^ ((row & 7) << 4)));
        }
#pragma unroll
        for (int m = 0; m < 4; ++m)
#pragma unroll
            for (int n = 0; n < 4; ++n) {
                acc[m][n] = __builtin_amdgcn_mfma_f32_16x16x32_bf16(af[m][0], bfr[n][0], acc[m][n], 0, 0, 0);
                acc[m][n] = __builtin_amdgcn_mfma_f32_16x16x32_bf16(af[m][1], bfr[n][1], acc[m][n], 0, 0, 0);
            }
        __syncthreads();
    }

#pragma unroll
    for (int m = 0; m < 4; ++m) {
#pragma unroll
        for (int n = 0; n < 4; ++n) {
            int col = bn + wc * 64 + n * 16 + lrow;
            float bv = bias[col];
#pragma unroll
            for (int r = 0; r < 4; ++r) {
                int row = bm + wr * 64 + m * 16 + lk * 4 + r;
                size_t off = (size_t)row * 1024 + col;
                float v = acc[m][n][r] + bv;
                if constexpr (MODE == 0) {
                    float mixv = 1.f / (1.f + __expf(-v));
                    float o = mixv * bf2f(A0[off]) + (1.f - mixv) * bf2f(A1[off]);
                    ((unsigned short*)Cout)[off] = f2bf(o);
                } else {
                    ((float*)Cout)[off] = v;
                }
            }
        }
    }
}

// ---------------------------------------------------------------- launch
extern "C" void kernel_launch(void* const* d_in, const int* in_sizes, int n_in,
                              void* d_out, int out_size, void* d_ws, size_t ws_size,
                              hipStream_t stream) {
    (void)in_sizes; (void)n_in; (void)out_size; (void)ws_size;
    const float* x     = (const float*)d_in[0];
    const float* pos   = (const float*)d_in[1];
    const float* gmem  = (const float*)d_in[2];
    const float* convw = (const float*)d_in[3];
    const float* convb = (const float*)d_in[4];
    const float* gatew = (const float*)d_in[5];
    const float* gateb = (const float*)d_in[6];
    const float* outw  = (const float*)d_in[7];
    const float* outb  = (const float*)d_in[8];

    float* ws = (float*)d_ws;
    float* gt   = ws;                                   //    524,288 f
    float* part = gt + 524288;                          //  1,048,576 f
    unsigned short* local_bf = (unsigned short*)(part + 1048576);  // 16M u16
    unsigned short* glob_bf  = local_bf + 16777216;                // 16M u16
    unsigned short* mixed_bf = glob_bf + 16777216;                 // 16M u16
    unsigned short* wTg      = mixed_bf + 16777216;                //  2M u16
    unsigned short* wTo      = wTg + 2097152;                      //  1M u16

    k_wtrans<2048><<<dim3(64, 32), 256, 0, stream>>>(gatew, wTg);
    k_wtrans<1024><<<dim3(32, 32), 256, 0, stream>>>(outw, wTo);
    k_winattn <<<B * NW * H * 4, 256, 0, stream>>>(x, pos, local_bf);
    k_conv_part<<<256, 256, 0, stream>>>(x, pos, convw, part);
    k_gt      <<<512, 256, 0, stream>>>(part, convb, gmem, gt);
    k_globattn<<<B * H * (S / 128), 256, 0, stream>>>(x, pos, gt, glob_bf);
    k_mgemm<0><<<1024, 256, 0, stream>>>(local_bf, glob_bf, wTg, gateb, mixed_bf);
    k_mgemm<1><<<1024, 256, 0, stream>>>(mixed_bf, nullptr, wTo, outb, d_out);
}